// Round 4
// baseline (162.310 us; speedup 1.0000x reference)
//
#include <hip/hip_runtime.h>
#include <hip/hip_bf16.h>

// Problem constants: N=4096, D=512, H=256, O=256, M=8, K=2, F=512, C=2
#define N_TOK 4096
#define D_IN  512
#define H_DIM 256
#define O_DIM 256
#define M_EXP 8
#define F_DIM 512

typedef __attribute__((ext_vector_type(8))) short bf16x8;   // 8 bf16 = 4 VGPRs (MFMA A/B frag)
typedef __attribute__((ext_vector_type(4))) float f32x4;    // MFMA C/D frag

// RNE f32 -> bf16 bits
__device__ __forceinline__ unsigned short f2bf(float f) {
    unsigned int u = __float_as_uint(f);
    u = (u + 0x7FFFu + ((u >> 16) & 1u)) >> 16;
    return (unsigned short)u;
}

// async global->LDS, 16B per lane (used by fuse kernel only)
__device__ __forceinline__ void gload_lds16(const void* g, void* l) {
    __builtin_amdgcn_global_load_lds(
        (const __attribute__((address_space(1))) unsigned int*)g,
        (__attribute__((address_space(3))) unsigned int*)l, 16, 0, 0);
}

// Swizzled LDS byte offsets. 64B rows (4x16B slots): slot ^= (row>>1)&3.
__device__ __forceinline__ int sw64(int row, int lslot) {
    return row * 64 + ((lslot ^ ((row >> 1) & 3)) << 4);
}
// Hs tile: 512B rows (32x16B slots): slot ^= row&7.
__device__ __forceinline__ int swHs(int row, int lslot) {
    return row * 512 + ((lslot ^ (row & 7)) << 4);
}

// ---------------------------------------------------------------------------
// Gating (f32-exact; reduction order identical across rounds so top-k never
// flips) + X f32->bf16 conversion fused (Xbf[2][4096][512]).
// ---------------------------------------------------------------------------
__global__ __launch_bounds__(256) void gate_kernel(
    const float* __restrict__ Xb, const float* __restrict__ Xc,
    const float* __restrict__ Wg, const float* __restrict__ bg,
    float* __restrict__ coef_b, float* __restrict__ coef_c,
    float* __restrict__ mask_b, float* __restrict__ mask_c,
    float* __restrict__ gsum, float* __restrict__ cnt,
    unsigned short* __restrict__ Xbf)
{
    const int mod = blockIdx.y;
    const float* X = mod ? Xc : Xb;
    float* coef = mod ? coef_c : coef_b;
    float* mask = mod ? mask_c : mask_b;
    const int wave = threadIdx.x >> 6;
    const int lane = threadIdx.x & 63;
    const int n = blockIdx.x * 4 + wave;

    __shared__ float s_g[M_EXP];
    __shared__ float s_c[M_EXP];
    if (threadIdx.x < M_EXP) { s_g[threadIdx.x] = 0.f; s_c[threadIdx.x] = 0.f; }
    __syncthreads();

    float acc[M_EXP] = {0.f,0.f,0.f,0.f,0.f,0.f,0.f,0.f};
    const float* xrow = X + (size_t)n * D_IN;
    unsigned short* xb = Xbf + (size_t)mod * N_TOK * D_IN + (size_t)n * D_IN;
#pragma unroll
    for (int k = 0; k < 8; ++k) {
        const int d = lane + 64 * k;
        const float xv = xrow[d];
        xb[d] = f2bf(xv);
        const float* wr = Wg + d * M_EXP;
#pragma unroll
        for (int m = 0; m < M_EXP; ++m) acc[m] += xv * wr[m];
    }
#pragma unroll
    for (int off = 1; off < 64; off <<= 1) {
#pragma unroll
        for (int m = 0; m < M_EXP; ++m) acc[m] += __shfl_xor(acc[m], off, 64);
    }
    float g[M_EXP];
    float mx = -1e30f;
#pragma unroll
    for (int m = 0; m < M_EXP; ++m) { g[m] = acc[m] + bg[m]; mx = fmaxf(mx, g[m]); }
    float es = 0.f;
#pragma unroll
    for (int m = 0; m < M_EXP; ++m) { g[m] = expf(g[m] - mx); es += g[m]; }
    const float inv = 1.f / es;
#pragma unroll
    for (int m = 0; m < M_EXP; ++m) g[m] *= inv;

    int i0 = 0; float v0 = g[0];
#pragma unroll
    for (int m = 1; m < M_EXP; ++m) if (g[m] > v0) { v0 = g[m]; i0 = m; }
    int i1 = -1; float v1 = -1e30f;
#pragma unroll
    for (int m = 0; m < M_EXP; ++m) if (m != i0 && g[m] > v1) { v1 = g[m]; i1 = m; }

    if (lane == 0) {
        const float wn = 1.f / (v0 + v1);
        coef[i0 * N_TOK + n] = v0 * wn;
        coef[i1 * N_TOK + n] = v1 * wn;
        mask[i0 * N_TOK + n] = 1.f;
        mask[i1 * N_TOK + n] = 1.f;
#pragma unroll
        for (int m = 0; m < M_EXP; ++m) atomicAdd(&s_g[m], g[m]);
        atomicAdd(&s_c[i0], 1.f);
        atomicAdd(&s_c[i1], 1.f);
    }
    __syncthreads();
    if (threadIdx.x < M_EXP) {
        atomicAdd(&gsum[mod * M_EXP + threadIdx.x], s_g[threadIdx.x]);
        atomicAdd(&cnt[mod * M_EXP + threadIdx.x], s_c[threadIdx.x]);
    }
}

// ---------------------------------------------------------------------------
// Merged prep: W1 transpose (blocks [0,1024)), W2 transpose ([1024,1536)),
// Wf fold+transpose ([1536,1792)), out init with bc ([1792,1824)).
// ---------------------------------------------------------------------------
__global__ __launch_bounds__(256) void prep_kernel(
    const float* __restrict__ W1, const float* __restrict__ W2,
    const float* __restrict__ Wf, const float* __restrict__ bc,
    unsigned short* __restrict__ W1T, unsigned short* __restrict__ W2T,
    unsigned short* __restrict__ WfT, float* __restrict__ out)
{
    __shared__ float tile[32][33];
    const int bx = blockIdx.x;
    const int tr = threadIdx.x >> 3, q = threadIdx.x & 7;
    if (bx < 1024) {            // W1 [8][512][256] -> W1T [8][256][512]
        const int e = bx >> 7, tidx = bx & 127;
        const int r0 = (tidx >> 3) * 32, c0 = (tidx & 7) * 32;
        const float* s = W1 + (size_t)e * 512 * 256;
        unsigned short* d = W1T + (size_t)e * 512 * 256;
        *(float4*)&tile[tr][q * 4] = *(const float4*)&s[(size_t)(r0 + tr) * 256 + c0 + q * 4];
        __syncthreads();
        ushort4 o;
        o.x = f2bf(tile[q*4+0][tr]); o.y = f2bf(tile[q*4+1][tr]);
        o.z = f2bf(tile[q*4+2][tr]); o.w = f2bf(tile[q*4+3][tr]);
        *(ushort4*)&d[(size_t)(c0 + tr) * 512 + r0 + q * 4] = o;
    } else if (bx < 1536) {     // W2 [8][256][256] -> W2T [8][256][256]
        const int idx = bx - 1024;
        const int e = idx >> 6, tidx = idx & 63;
        const int r0 = (tidx >> 3) * 32, c0 = (tidx & 7) * 32;
        const float* s = W2 + (size_t)e * 256 * 256;
        unsigned short* d = W2T + (size_t)e * 256 * 256;
        *(float4*)&tile[tr][q * 4] = *(const float4*)&s[(size_t)(r0 + tr) * 256 + c0 + q * 4];
        __syncthreads();
        ushort4 o;
        o.x = f2bf(tile[q*4+0][tr]); o.y = f2bf(tile[q*4+1][tr]);
        o.z = f2bf(tile[q*4+2][tr]); o.w = f2bf(tile[q*4+3][tr]);
        *(ushort4*)&d[(size_t)(c0 + tr) * 256 + r0 + q * 4] = o;
    } else if (bx < 1792) {     // WfT_eff[f][j] = Wf[j][f] + (j>=256 ? Wf[j+256][f] : 0)
        const int idx = bx - 1536;
        const int j0 = (idx >> 4) * 32, f0 = (idx & 15) * 32;
        float4 v = *(const float4*)&Wf[(size_t)(j0 + tr) * F_DIM + f0 + q * 4];
        if (j0 >= 256) {
            const float4 v2 = *(const float4*)&Wf[(size_t)(j0 + tr + 256) * F_DIM + f0 + q * 4];
            v.x += v2.x; v.y += v2.y; v.z += v2.z; v.w += v2.w;
        }
        *(float4*)&tile[tr][q * 4] = v;
        __syncthreads();
        ushort4 o;
        o.x = f2bf(tile[q*4+0][tr]); o.y = f2bf(tile[q*4+1][tr]);
        o.z = f2bf(tile[q*4+2][tr]); o.w = f2bf(tile[q*4+3][tr]);
        *(ushort4*)&WfT[(size_t)(f0 + tr) * 512 + j0 + q * 4] = o;
    } else {                    // out init
        const int i = (bx - 1792) * 256 + threadIdx.x;
        out[i] = bc[i & 1];
    }
}

// ---------------------------------------------------------------------------
// Expert MLPs via MFMA, barrier-free operand streaming. Grid (64 tiles, 16
// mod-expert pairs). BM=64, BN=256, 4 waves x (64x64). A- and B-fragments are
// loaded DIRECTLY global->VGPR (weights have zero cross-wave reuse; X is
// L1/L2-hot). Only Hs lives in LDS (32KB -> high occupancy); exactly ONE
// __syncthreads per block (h->y transition). Compiler software-pipelines the
// unrolled K-loop loads with fine-grained vmcnt.
// ---------------------------------------------------------------------------
__global__ __launch_bounds__(256) void expert_mfma_kernel(
    const unsigned short* __restrict__ Xbf,
    const unsigned short* __restrict__ W1T, const unsigned short* __restrict__ W2T,
    const float* __restrict__ b1, const float* __restrict__ b2,
    const float* __restrict__ coef_b, const float* __restrict__ coef_c,
    const float* __restrict__ mask_b, const float* __restrict__ mask_c,
    float* __restrict__ out_b, float* __restrict__ out_c,
    float* __restrict__ sum_out)
{
    __shared__ __align__(16) char Hs[64 * 512];   // [64 rows][256 bf16], swizzled, 32KB

    const int t = threadIdx.x;
    const int w = t >> 6, l = t & 63;
    const int lr = l & 15, lk = l >> 4;
    const int pair = blockIdx.y;
    const int m = pair & 7;
    const int mod = pair >> 3;
    const float* coef = mod ? coef_c : coef_b;
    const float* mask = mod ? mask_c : mask_b;
    float* outp = mod ? out_c : out_b;
    const float modw = mod ? 2.f : 1.f;
    const int base = blockIdx.x * 64;
    const int wcol = w * 64;

    const unsigned short* xmod = Xbf + (size_t)mod * N_TOK * D_IN;
    const unsigned short* w1p = W1T + (size_t)m * H_DIM * D_IN;
    const unsigned short* w2p = W2T + (size_t)m * O_DIM * H_DIM;

    f32x4 acc[4][4];

    // ================= h phase: K=512, 16 chunks, no barriers =================
#pragma unroll
    for (int nj = 0; nj < 4; ++nj) {
        const float bv = b1[m * H_DIM + wcol + nj * 16 + lr];
#pragma unroll
        for (int mi = 0; mi < 4; ++mi) { f32x4 z = {bv, bv, bv, bv}; acc[mi][nj] = z; }
    }
    // per-lane base element offsets (A: row base+mi*16+lr; B: col wcol+nj*16+lr)
#pragma unroll 4
    for (int kc = 0; kc < 16; ++kc) {
        bf16x8 a[4], b[4];
#pragma unroll
        for (int mi = 0; mi < 4; ++mi)
            a[mi] = *(const bf16x8*)(xmod + (size_t)(base + mi * 16 + lr) * D_IN + kc * 32 + lk * 8);
#pragma unroll
        for (int nj = 0; nj < 4; ++nj)
            b[nj] = *(const bf16x8*)(w1p + (size_t)(wcol + nj * 16 + lr) * D_IN + kc * 32 + lk * 8);
#pragma unroll
        for (int mi = 0; mi < 4; ++mi)
#pragma unroll
            for (int nj = 0; nj < 4; ++nj)
                acc[mi][nj] = __builtin_amdgcn_mfma_f32_16x16x32_bf16(a[mi], b[nj], acc[mi][nj], 0, 0, 0);
    }

    // relu -> Hs (bf16, swizzled). D-frag: row=(lk*4+reg), col=lr within 16x16.
#pragma unroll
    for (int mi = 0; mi < 4; ++mi)
#pragma unroll
        for (int nj = 0; nj < 4; ++nj) {
            const int col = wcol + nj * 16 + lr;
            const int cslot = col >> 3;
            const int cbyte = (col & 7) * 2;
#pragma unroll
            for (int j = 0; j < 4; ++j) {
                const int row = mi * 16 + lk * 4 + j;
                *(unsigned short*)&Hs[row * 512 + ((cslot ^ (row & 7)) << 4) + cbyte] =
                    f2bf(fmaxf(acc[mi][nj][j], 0.f));
            }
        }
    __syncthreads();   // the ONLY block barrier

    // ================= y phase: K=256, 8 chunks, no barriers =================
#pragma unroll
    for (int nj = 0; nj < 4; ++nj) {
        const float bv = b2[m * O_DIM + wcol + nj * 16 + lr];
#pragma unroll
        for (int mi = 0; mi < 4; ++mi) { f32x4 z = {bv, bv, bv, bv}; acc[mi][nj] = z; }
    }
#pragma unroll 4
    for (int kc = 0; kc < 8; ++kc) {
        bf16x8 a[4], b[4];
#pragma unroll
        for (int mi = 0; mi < 4; ++mi)
            a[mi] = *(const bf16x8*)&Hs[swHs(mi * 16 + lr, kc * 4 + lk)];
#pragma unroll
        for (int nj = 0; nj < 4; ++nj)
            b[nj] = *(const bf16x8*)(w2p + (size_t)(wcol + nj * 16 + lr) * H_DIM + kc * 32 + lk * 8);
#pragma unroll
        for (int mi = 0; mi < 4; ++mi)
#pragma unroll
            for (int nj = 0; nj < 4; ++nj)
                acc[mi][nj] = __builtin_amdgcn_mfma_f32_16x16x32_bf16(a[mi], b[nj], acc[mi][nj], 0, 0, 0);
    }

    // ============ epilogue: top-k combine + masked column sums ============
    float sacc[4] = {0.f, 0.f, 0.f, 0.f};
#pragma unroll
    for (int mi = 0; mi < 4; ++mi)
#pragma unroll
        for (int j = 0; j < 4; ++j) {
            const int lrow = mi * 16 + lk * 4 + j;
            const float cf = coef[(size_t)m * N_TOK + base + lrow];
            const float mk = mask[(size_t)m * N_TOK + base + lrow];
            const size_t grow = (size_t)(base + lrow) * O_DIM;
#pragma unroll
            for (int nj = 0; nj < 4; ++nj) {
                const float v = acc[mi][nj][j];
                if (cf != 0.f) atomicAdd(&outp[grow + wcol + nj * 16 + lr], cf * v);
                sacc[nj] = fmaf(mk, v, sacc[nj]);
            }
        }
#pragma unroll
    for (int nj = 0; nj < 4; ++nj) {
        sacc[nj] += __shfl_xor(sacc[nj], 16, 64);
        sacc[nj] += __shfl_xor(sacc[nj], 32, 64);
    }
    if (lk == 0) {
#pragma unroll
        for (int nj = 0; nj < 4; ++nj)
            atomicAdd(&sum_out[m * O_DIM + wcol + nj * 16 + lr], sacc[nj] * modw);
    }
}

// ---------------------------------------------------------------------------
// Fusion + classifier, fused (unchanged).
// ---------------------------------------------------------------------------
__global__ __launch_bounds__(256, 4) void fuse_cls_kernel(
    const float* __restrict__ out_b, const float* __restrict__ out_c,
    const unsigned short* __restrict__ WfT, const float* __restrict__ bf,
    const float* __restrict__ Wc, float* __restrict__ out)
{
    __shared__ __align__(16) char As[32 * 64];
    __shared__ __align__(16) char Ws[256 * 64];
    const int t = threadIdx.x;
    const int w = t >> 6;
    const int l = t & 63;
    const int lr = l & 15, lk = l >> 4;
    const int base = blockIdx.x * 32;
    const int half = blockIdx.y;
    const int colbase = half * 256 + w * 64;

    f32x4 acc[2][4] = {};

    const int arow = t >> 2;
    const int aslot = (t & 3) ^ ((arow >> 1) & 3);
    const int wrow_l = l >> 2;
    const int wpslot = l & 3;

    for (int kc = 0; kc < 16; ++kc) {
        __syncthreads();
        if (t < 128) {
            const int gk = kc * 32 + aslot * 8;
            const float* src = (gk < 256 ? out_b : out_c) + (size_t)(base + arow) * 256 + (gk & 255);
            const float4 f0 = *(const float4*)src;
            const float4 f1 = *(const float4*)(src + 4);
            bf16x8 p;
            p[0] = (short)f2bf(f0.x); p[1] = (short)f2bf(f0.y);
            p[2] = (short)f2bf(f0.z); p[3] = (short)f2bf(f0.w);
            p[4] = (short)f2bf(f1.x); p[5] = (short)f2bf(f1.y);
            p[6] = (short)f2bf(f1.z); p[7] = (short)f2bf(f1.w);
            *(bf16x8*)&As[t * 16] = p;
        }
#pragma unroll
        for (int s2 = 0; s2 < 4; ++s2) {
            const int row = w * 64 + s2 * 16 + wrow_l;
            const int lslot = wpslot ^ ((row >> 1) & 3);
            gload_lds16(WfT + (size_t)(half * 256 + row) * 512 + kc * 32 + lslot * 8,
                        &Ws[w * 4096 + s2 * 1024]);
        }
        __syncthreads();
        bf16x8 a[2], b[4];
#pragma unroll
        for (int mi = 0; mi < 2; ++mi)
            a[mi] = *(const bf16x8*)&As[sw64(mi * 16 + lr, lk)];
#pragma unroll
        for (int nj = 0; nj < 4; ++nj)
            b[nj] = *(const bf16x8*)&Ws[sw64(w * 64 + nj * 16 + lr, lk)];
#pragma unroll
        for (int mi = 0; mi < 2; ++mi)
#pragma unroll
            for (int nj = 0; nj < 4; ++nj)
                acc[mi][nj] = __builtin_amdgcn_mfma_f32_16x16x32_bf16(a[mi], b[nj], acc[mi][nj], 0, 0, 0);
    }

#pragma unroll
    for (int mi = 0; mi < 2; ++mi)
#pragma unroll
        for (int j = 0; j < 4; ++j) {
            float p0 = 0.f, p1 = 0.f;
#pragma unroll
            for (int nj = 0; nj < 4; ++nj) {
                const int col = colbase + nj * 16 + lr;
                const float r = fmaxf(acc[mi][nj][j] + bf[col], 0.f);
                p0 = fmaf(r, Wc[col * 2 + 0], p0);
                p1 = fmaf(r, Wc[col * 2 + 1], p1);
            }
#pragma unroll
            for (int off = 1; off < 16; off <<= 1) {
                p0 += __shfl_xor(p0, off, 64);
                p1 += __shfl_xor(p1, off, 64);
            }
            if (lr == 0) {
                const int row = base + mi * 16 + lk * 4 + j;
                atomicAdd(&out[row * 2 + 0], p0);
                atomicAdd(&out[row * 2 + 1], p1);
            }
        }
}

// ---------------------------------------------------------------------------
// Losses (unchanged).
// ---------------------------------------------------------------------------
__global__ __launch_bounds__(256) void loss_kernel(
    const float* __restrict__ gsum, const float* __restrict__ cnt,
    const float* __restrict__ sum_out, float* __restrict__ dout)
{
    __shared__ float avg[M_EXP][O_DIM];
    __shared__ float rho_s[M_EXP];
    __shared__ float simv[28];
    __shared__ float prs[28];
    const int t = threadIdx.x;
    if (t < M_EXP) rho_s[t] = cnt[t] + 2.f * cnt[M_EXP + t];
    __syncthreads();
    for (int idx = t; idx < M_EXP * O_DIM; idx += 256) {
        const int m = idx >> 8;
        avg[m][idx & 255] = sum_out[idx] / fmaxf(rho_s[m], 1.f);
    }
    __syncthreads();
    if (t < 28) {
        int a = 0, p = t;
        while (p >= 7 - a) { p -= 7 - a; ++a; }
        const int b = a + 1 + p;
        float d2 = 0.f;
        for (int o = 0; o < O_DIM; ++o) {
            const float df = avg[a][o] - avg[b][o];
            d2 = fmaf(df, df, d2);
        }
        const bool pr = (rho_s[a] > 0.f) && (rho_s[b] > 0.f);
        simv[t] = pr ? expf(-0.5f * d2) : 0.f;
        prs[t]  = pr ? 1.f : 0.f;
    }
    __syncthreads();
    if (t == 0) {
        float s = 0.f, np = 0.f;
        for (int p = 0; p < 28; ++p) { s += simv[p]; np += prs[p]; }
        dout[N_TOK * 2 + 0] = -s / fmaxf(np, 1.f);
        float eq = 0.f;
        for (int m = 0; m < M_EXP; ++m) {
            const float rho = cnt[m] + 2.f * cnt[M_EXP + m];
            const float rh  = gsum[m] + 2.f * gsum[M_EXP + m];
            eq = fmaf(rho, rh, eq);
        }
        dout[N_TOK * 2 + 1] = eq / (float)M_EXP;
    }
}

// ---------------------------------------------------------------------------
extern "C" void kernel_launch(void* const* d_in, const int* in_sizes, int n_in,
                              void* d_out, int out_size, void* d_ws, size_t ws_size,
                              hipStream_t stream)
{
    const float* Xb = (const float*)d_in[0];
    const float* Xc = (const float*)d_in[1];
    // d_in[2] (vec_fcg) intentionally unused: reference source bug reuses cfg.
    const float* Wg = (const float*)d_in[3];
    const float* bg = (const float*)d_in[4];
    const float* W1 = (const float*)d_in[5];
    const float* b1 = (const float*)d_in[6];
    const float* W2 = (const float*)d_in[7];
    const float* b2 = (const float*)d_in[8];
    const float* Wf = (const float*)d_in[9];
    const float* bf = (const float*)d_in[10];
    const float* Wc = (const float*)d_in[11];
    const float* bc = (const float*)d_in[12];
    float* out = (float*)d_out;

    float* ws = (float*)d_ws;
    float* coef_b  = ws;                           // 32768
    float* coef_c  = coef_b + M_EXP * N_TOK;
    float* mask_b  = coef_c + M_EXP * N_TOK;
    float* mask_c  = mask_b + M_EXP * N_TOK;
    float* gsum    = mask_c + M_EXP * N_TOK;       // [2][8]
    float* cnt     = gsum + 16;                    // [2][8]
    float* sum_out = cnt + 16;                     // [8][256]
    float* out_b   = sum_out + M_EXP * O_DIM;      // [4096][256] f32 (atomic)
    float* out_c   = out_b + (size_t)N_TOK * O_DIM;
    unsigned short* W1T = (unsigned short*)(out_c + (size_t)N_TOK * O_DIM); // [8][256][512]
    unsigned short* W2T = W1T + (size_t)M_EXP * H_DIM * D_IN;              // [8][256][256]
    unsigned short* WfT = W2T + (size_t)M_EXP * O_DIM * H_DIM;             // [512][512]
    unsigned short* Xbf = WfT + (size_t)F_DIM * 512;                       // [2][4096][512]

    // zero atomic-accumulated regions (coef..sum_out + out_b + out_c)
    const size_t zero_f = (size_t)(4 * M_EXP * N_TOK + 32 + M_EXP * O_DIM) + 2 * (size_t)N_TOK * O_DIM;
    hipMemsetAsync(d_ws, 0, zero_f * sizeof(float), stream);

    prep_kernel<<<dim3(1824), 256, 0, stream>>>(W1, W2, Wf, bc, W1T, W2T, WfT, out);
    gate_kernel<<<dim3(N_TOK / 4, 2), 256, 0, stream>>>(
        Xb, Xc, Wg, bg, coef_b, coef_c, mask_b, mask_c, gsum, cnt, Xbf);
    expert_mfma_kernel<<<dim3(N_TOK / 64, 16), 256, 0, stream>>>(
        Xbf, W1T, W2T, b1, b2, coef_b, coef_c, mask_b, mask_c, out_b, out_c, sum_out);
    fuse_cls_kernel<<<dim3(N_TOK / 32, 2), 256, 0, stream>>>(out_b, out_c, WfT, bf, Wc, out);
    loss_kernel<<<1, 256, 0, stream>>>(gsum, cnt, sum_out, out);
}

// Round 5
// 122.229 us; speedup vs baseline: 1.3279x; 1.3279x over previous
//
#include <hip/hip_runtime.h>
#include <hip/hip_bf16.h>

// Problem constants: N=4096, D=512, H=256, O=256, M=8, K=2, F=512, C=2
#define N_TOK 4096
#define D_IN  512
#define H_DIM 256
#define O_DIM 256
#define M_EXP 8
#define F_DIM 512

typedef __attribute__((ext_vector_type(8))) short bf16x8;   // 8 bf16 = 4 VGPRs (MFMA A/B frag)
typedef __attribute__((ext_vector_type(4))) float f32x4;    // MFMA C/D frag

#define VMCNT(n)  asm volatile("s_waitcnt vmcnt(" #n ")" ::: "memory")
#define LGKMCNT0  asm volatile("s_waitcnt lgkmcnt(0)" ::: "memory")
#define BARRIER() __builtin_amdgcn_s_barrier()

// RNE f32 -> bf16 bits
__device__ __forceinline__ unsigned short f2bf(float f) {
    unsigned int u = __float_as_uint(f);
    u = (u + 0x7FFFu + ((u >> 16) & 1u)) >> 16;
    return (unsigned short)u;
}

// async global->LDS, 16B per lane; LDS dest wave-uniform base + lane*16
__device__ __forceinline__ void gload_lds16(const void* g, void* l) {
    __builtin_amdgcn_global_load_lds(
        (const __attribute__((address_space(1))) unsigned int*)g,
        (__attribute__((address_space(3))) unsigned int*)l, 16, 0, 0);
}

// Swizzled LDS byte offsets. 64B rows (4x16B slots): slot ^= (row>>1)&3.
__device__ __forceinline__ int sw64(int row, int lslot) {
    return row * 64 + ((lslot ^ ((row >> 1) & 3)) << 4);
}
// 512B rows (32x16B slots): slot ^= row&7.
__device__ __forceinline__ int swHs(int row, int lslot) {
    return row * 512 + ((lslot ^ (row & 7)) << 4);
}
// 1024B rows (64x16B slots): slot ^= row&7 (low 3 bits).
__device__ __forceinline__ int swAs(int row, int lslot) {
    return row * 1024 + ((lslot ^ (row & 7)) << 4);
}

// ---------------------------------------------------------------------------
// Gating (f32-exact; reduction order identical across rounds so top-k never
// flips) + X f32->bf16 conversion fused (Xbf[2][4096][512]).
// ---------------------------------------------------------------------------
__global__ __launch_bounds__(256) void gate_kernel(
    const float* __restrict__ Xb, const float* __restrict__ Xc,
    const float* __restrict__ Wg, const float* __restrict__ bg,
    float* __restrict__ coef_b, float* __restrict__ coef_c,
    float* __restrict__ mask_b, float* __restrict__ mask_c,
    float* __restrict__ gsum, float* __restrict__ cnt,
    unsigned short* __restrict__ Xbf)
{
    const int mod = blockIdx.y;
    const float* X = mod ? Xc : Xb;
    float* coef = mod ? coef_c : coef_b;
    float* mask = mod ? mask_c : mask_b;
    const int wave = threadIdx.x >> 6;
    const int lane = threadIdx.x & 63;
    const int n = blockIdx.x * 4 + wave;

    __shared__ float s_g[M_EXP];
    __shared__ float s_c[M_EXP];
    if (threadIdx.x < M_EXP) { s_g[threadIdx.x] = 0.f; s_c[threadIdx.x] = 0.f; }
    __syncthreads();

    float acc[M_EXP] = {0.f,0.f,0.f,0.f,0.f,0.f,0.f,0.f};
    const float* xrow = X + (size_t)n * D_IN;
    unsigned short* xb = Xbf + (size_t)mod * N_TOK * D_IN + (size_t)n * D_IN;
#pragma unroll
    for (int k = 0; k < 8; ++k) {
        const int d = lane + 64 * k;
        const float xv = xrow[d];
        xb[d] = f2bf(xv);
        const float* wr = Wg + d * M_EXP;
#pragma unroll
        for (int m = 0; m < M_EXP; ++m) acc[m] += xv * wr[m];
    }
#pragma unroll
    for (int off = 1; off < 64; off <<= 1) {
#pragma unroll
        for (int m = 0; m < M_EXP; ++m) acc[m] += __shfl_xor(acc[m], off, 64);
    }
    float g[M_EXP];
    float mx = -1e30f;
#pragma unroll
    for (int m = 0; m < M_EXP; ++m) { g[m] = acc[m] + bg[m]; mx = fmaxf(mx, g[m]); }
    float es = 0.f;
#pragma unroll
    for (int m = 0; m < M_EXP; ++m) { g[m] = expf(g[m] - mx); es += g[m]; }
    const float inv = 1.f / es;
#pragma unroll
    for (int m = 0; m < M_EXP; ++m) g[m] *= inv;

    int i0 = 0; float v0 = g[0];
#pragma unroll
    for (int m = 1; m < M_EXP; ++m) if (g[m] > v0) { v0 = g[m]; i0 = m; }
    int i1 = -1; float v1 = -1e30f;
#pragma unroll
    for (int m = 0; m < M_EXP; ++m) if (m != i0 && g[m] > v1) { v1 = g[m]; i1 = m; }

    if (lane == 0) {
        const float wn = 1.f / (v0 + v1);
        coef[i0 * N_TOK + n] = v0 * wn;
        coef[i1 * N_TOK + n] = v1 * wn;
        mask[i0 * N_TOK + n] = 1.f;
        mask[i1 * N_TOK + n] = 1.f;
#pragma unroll
        for (int m = 0; m < M_EXP; ++m) atomicAdd(&s_g[m], g[m]);
        atomicAdd(&s_c[i0], 1.f);
        atomicAdd(&s_c[i1], 1.f);
    }
    __syncthreads();
    if (threadIdx.x < M_EXP) {
        atomicAdd(&gsum[mod * M_EXP + threadIdx.x], s_g[threadIdx.x]);
        atomicAdd(&cnt[mod * M_EXP + threadIdx.x], s_c[threadIdx.x]);
    }
}

// ---------------------------------------------------------------------------
// Merged prep (unchanged): W1T, W2T, WfT_eff, out init.
// ---------------------------------------------------------------------------
__global__ __launch_bounds__(256) void prep_kernel(
    const float* __restrict__ W1, const float* __restrict__ W2,
    const float* __restrict__ Wf, const float* __restrict__ bc,
    unsigned short* __restrict__ W1T, unsigned short* __restrict__ W2T,
    unsigned short* __restrict__ WfT, float* __restrict__ out)
{
    __shared__ float tile[32][33];
    const int bx = blockIdx.x;
    const int tr = threadIdx.x >> 3, q = threadIdx.x & 7;
    if (bx < 1024) {            // W1 [8][512][256] -> W1T [8][256][512]
        const int e = bx >> 7, tidx = bx & 127;
        const int r0 = (tidx >> 3) * 32, c0 = (tidx & 7) * 32;
        const float* s = W1 + (size_t)e * 512 * 256;
        unsigned short* d = W1T + (size_t)e * 512 * 256;
        *(float4*)&tile[tr][q * 4] = *(const float4*)&s[(size_t)(r0 + tr) * 256 + c0 + q * 4];
        __syncthreads();
        ushort4 o;
        o.x = f2bf(tile[q*4+0][tr]); o.y = f2bf(tile[q*4+1][tr]);
        o.z = f2bf(tile[q*4+2][tr]); o.w = f2bf(tile[q*4+3][tr]);
        *(ushort4*)&d[(size_t)(c0 + tr) * 512 + r0 + q * 4] = o;
    } else if (bx < 1536) {     // W2 [8][256][256] -> W2T [8][256][256]
        const int idx = bx - 1024;
        const int e = idx >> 6, tidx = idx & 63;
        const int r0 = (tidx >> 3) * 32, c0 = (tidx & 7) * 32;
        const float* s = W2 + (size_t)e * 256 * 256;
        unsigned short* d = W2T + (size_t)e * 256 * 256;
        *(float4*)&tile[tr][q * 4] = *(const float4*)&s[(size_t)(r0 + tr) * 256 + c0 + q * 4];
        __syncthreads();
        ushort4 o;
        o.x = f2bf(tile[q*4+0][tr]); o.y = f2bf(tile[q*4+1][tr]);
        o.z = f2bf(tile[q*4+2][tr]); o.w = f2bf(tile[q*4+3][tr]);
        *(ushort4*)&d[(size_t)(c0 + tr) * 256 + r0 + q * 4] = o;
    } else if (bx < 1792) {     // WfT_eff[f][j] = Wf[j][f] + (j>=256 ? Wf[j+256][f] : 0)
        const int idx = bx - 1536;
        const int j0 = (idx >> 4) * 32, f0 = (idx & 15) * 32;
        float4 v = *(const float4*)&Wf[(size_t)(j0 + tr) * F_DIM + f0 + q * 4];
        if (j0 >= 256) {
            const float4 v2 = *(const float4*)&Wf[(size_t)(j0 + tr + 256) * F_DIM + f0 + q * 4];
            v.x += v2.x; v.y += v2.y; v.z += v2.z; v.w += v2.w;
        }
        *(float4*)&tile[tr][q * 4] = v;
        __syncthreads();
        ushort4 o;
        o.x = f2bf(tile[q*4+0][tr]); o.y = f2bf(tile[q*4+1][tr]);
        o.z = f2bf(tile[q*4+2][tr]); o.w = f2bf(tile[q*4+3][tr]);
        *(ushort4*)&WfT[(size_t)(f0 + tr) * 512 + j0 + q * 4] = o;
    } else {                    // out init
        const int i = (bx - 1792) * 256 + threadIdx.x;
        out[i] = bc[i & 1];
    }
}

// ---------------------------------------------------------------------------
// Expert MLPs via MFMA with T3+T4 counted-vmcnt double-buffered pipeline.
// Grid 1024 (XCD-swizzled). 1 expert per block, BM=64, BN=256, BK=32, 4 waves.
// Per chunk: issue next stage (5 gload_lds) -> vmcnt(5) -> s_barrier ->
// ds_read+16 MFMA -> s_barrier. Loads stay in flight across barriers.
// LDS 72KB -> 2 blocks/CU. Biases preloaded+drained before pipeline so no
// stray VMEM perturbs vmcnt counts.
// ---------------------------------------------------------------------------
__global__ __launch_bounds__(256, 2) void expert_mfma_kernel(
    const unsigned short* __restrict__ Xbf,
    const unsigned short* __restrict__ W1T, const unsigned short* __restrict__ W2T,
    const float* __restrict__ b1, const float* __restrict__ b2,
    const float* __restrict__ coef_b, const float* __restrict__ coef_c,
    const float* __restrict__ mask_b, const float* __restrict__ mask_c,
    float* __restrict__ out_b, float* __restrict__ out_c,
    float* __restrict__ sum_out)
{
    __shared__ __align__(16) char Xs[2][4096];    // [64 rows][32 bf16] x2
    __shared__ __align__(16) char Ws[2][16384];   // [256 rows][32 bf16] x2
    __shared__ __align__(16) char Hs[32768];      // [64 rows][256 bf16]

    const int t = threadIdx.x;
    const int w = t >> 6, l = t & 63;
    const int lr = l & 15, lk = l >> 4;

    // XCD-aware bijective swizzle: 1024 blocks, 8 XCDs, 128/XCD ->
    // each XCD handles 2 consecutive (mod,expert) pairs (weights L2-resident).
    const int wid = (blockIdx.x & 7) * 128 + (blockIdx.x >> 3);
    const int pair = wid >> 6;          // [0,16)
    const int tile = wid & 63;          // [0,64)
    const int m = pair & 7;
    const int mod = pair >> 3;
    const float* coef = mod ? coef_c : coef_b;
    const float* mask = mod ? mask_c : mask_b;
    float* outp = mod ? out_c : out_b;
    const float modw = mod ? 2.f : 1.f;
    const int base = tile * 64;
    const int wcol = w * 64;

    const unsigned short* w1p = W1T + (size_t)m * H_DIM * D_IN;
    const unsigned short* w2p = W2T + (size_t)m * O_DIM * H_DIM;

    // ---- bias preload, drained BEFORE pipeline (keeps vmcnt counts exact) ----
    float bv1[4], bv2[4];
#pragma unroll
    for (int nj = 0; nj < 4; ++nj) {
        bv1[nj] = b1[m * H_DIM + wcol + nj * 16 + lr];
        bv2[nj] = b2[m * O_DIM + wcol + nj * 16 + lr];
    }
    VMCNT(0);
#pragma unroll
    for (int nj = 0; nj < 4; ++nj)
        asm volatile("" :: "v"(bv1[nj]), "v"(bv2[nj]));   // force materialization now

    // ---- staging geometry ----
    const int xrow = t >> 2;                           // [0,64)
    const int xls  = (t & 3) ^ ((xrow >> 1) & 3);      // pre-swizzled source slot
    const unsigned short* xsrc =
        Xbf + (size_t)mod * N_TOK * D_IN + (size_t)(base + xrow) * D_IN + xls * 8;
    const int wrow_l = l >> 2;
    const int wp = l & 3;

    auto stage_x = [&](int kc, int buf) {
        gload_lds16(xsrc + kc * 32, &Xs[buf][w * 1024]);   // wave-uniform dest base
    };
    auto stage_w = [&](const unsigned short* wbase, int rowlen, int kc, int buf) {
#pragma unroll
        for (int s2 = 0; s2 < 4; ++s2) {
            const int row = w * 64 + s2 * 16 + wrow_l;
            const int lslot = wp ^ ((row >> 1) & 3);
            gload_lds16(wbase + (size_t)row * rowlen + kc * 32 + lslot * 8,
                        &Ws[buf][w * 4096 + s2 * 1024]);
        }
    };

    f32x4 acc[4][4];
#pragma unroll
    for (int mi = 0; mi < 4; ++mi)
#pragma unroll
        for (int nj = 0; nj < 4; ++nj) { f32x4 z = {0.f,0.f,0.f,0.f}; acc[mi][nj] = z; }

    int cur = 0;
    stage_x(0, 0);
    stage_w(w1p, 512, 0, 0);      // 5 ops outstanding

    // ================= h phase: 16 chunks of K=32 =================
#pragma unroll
    for (int kc = 0; kc < 16; ++kc) {
        const int nb = cur ^ 1;
        if (kc < 15) {
            stage_x(kc + 1, nb);
            stage_w(w1p, 512, kc + 1, nb);   // +5 -> 10 outstanding
            VMCNT(5);                        // previous chunk's 5 landed
        } else {
            stage_w(w2p, 256, 0, nb);        // +4 -> 9 outstanding
            VMCNT(4);
        }
        BARRIER();
        bf16x8 a[4], b[4];
#pragma unroll
        for (int mi = 0; mi < 4; ++mi)
            a[mi] = *(const bf16x8*)&Xs[cur][sw64(mi * 16 + lr, lk)];
#pragma unroll
        for (int nj = 0; nj < 4; ++nj)
            b[nj] = *(const bf16x8*)&Ws[cur][sw64(wcol + nj * 16 + lr, lk)];
#pragma unroll
        for (int mi = 0; mi < 4; ++mi)
#pragma unroll
            for (int nj = 0; nj < 4; ++nj)
                acc[mi][nj] = __builtin_amdgcn_mfma_f32_16x16x32_bf16(a[mi], b[nj], acc[mi][nj], 0, 0, 0);
        if (kc == 15) {
            // h = relu(acc + b1) -> Hs (bf16, swizzled)
#pragma unroll
            for (int mi = 0; mi < 4; ++mi)
#pragma unroll
                for (int nj = 0; nj < 4; ++nj) {
                    const int col = wcol + nj * 16 + lr;
                    const int cslot = col >> 3;
                    const int cbyte = (col & 7) * 2;
#pragma unroll
                    for (int j = 0; j < 4; ++j) {
                        const int row = mi * 16 + lk * 4 + j;
                        *(unsigned short*)&Hs[row * 512 + ((cslot ^ (row & 7)) << 4) + cbyte] =
                            f2bf(fmaxf(acc[mi][nj][j] + bv1[nj], 0.f));
                    }
                }
            LGKMCNT0;   // Hs writes retired before publishing at barrier
        }
        BARRIER();
        cur = nb;
    }

#pragma unroll
    for (int mi = 0; mi < 4; ++mi)
#pragma unroll
        for (int nj = 0; nj < 4; ++nj) { f32x4 z = {0.f,0.f,0.f,0.f}; acc[mi][nj] = z; }

    // ================= y phase: 8 chunks of K=32 =================
#pragma unroll
    for (int kc = 0; kc < 8; ++kc) {
        const int nb = cur ^ 1;
        if (kc < 7) {
            stage_w(w2p, 256, kc + 1, nb);   // +4 -> 8 outstanding
            VMCNT(4);
        } else {
            VMCNT(0);                        // drain final chunk
        }
        BARRIER();
        bf16x8 a[4], b[4];
#pragma unroll
        for (int mi = 0; mi < 4; ++mi)
            a[mi] = *(const bf16x8*)&Hs[swHs(mi * 16 + lr, kc * 4 + lk)];
#pragma unroll
        for (int nj = 0; nj < 4; ++nj)
            b[nj] = *(const bf16x8*)&Ws[cur][sw64(wcol + nj * 16 + lr, lk)];
#pragma unroll
        for (int mi = 0; mi < 4; ++mi)
#pragma unroll
            for (int nj = 0; nj < 4; ++nj)
                acc[mi][nj] = __builtin_amdgcn_mfma_f32_16x16x32_bf16(a[mi], b[nj], acc[mi][nj], 0, 0, 0);
        BARRIER();
        cur = nb;
    }

    // ============ epilogue: top-k combine + masked column sums ============
    float sacc[4] = {0.f, 0.f, 0.f, 0.f};
#pragma unroll
    for (int mi = 0; mi < 4; ++mi)
#pragma unroll
        for (int j = 0; j < 4; ++j) {
            const int lrow = mi * 16 + lk * 4 + j;
            const float cf = coef[(size_t)m * N_TOK + base + lrow];
            const float mk = mask[(size_t)m * N_TOK + base + lrow];
            const size_t grow = (size_t)(base + lrow) * O_DIM;
#pragma unroll
            for (int nj = 0; nj < 4; ++nj) {
                const float v = acc[mi][nj][j] + bv2[nj];
                if (cf != 0.f) atomicAdd(&outp[grow + wcol + nj * 16 + lr], cf * v);
                sacc[nj] = fmaf(mk, v, sacc[nj]);
            }
        }
#pragma unroll
    for (int nj = 0; nj < 4; ++nj) {
        sacc[nj] += __shfl_xor(sacc[nj], 16, 64);
        sacc[nj] += __shfl_xor(sacc[nj], 32, 64);
    }
    if (lk == 0) {
#pragma unroll
        for (int nj = 0; nj < 4; ++nj)
            atomicAdd(&sum_out[m * O_DIM + wcol + nj * 16 + lr], sacc[nj] * modw);
    }
}

// ---------------------------------------------------------------------------
// Fusion + classifier: A-tile (32 rows x 512, [out_b|out_c]) converted to bf16
// LDS once up front; W-loop double-buffered with counted vmcnt(4).
// Grid (128 row-tiles, 2 f-halves). BM=32, BN=256, 4 waves.
// ---------------------------------------------------------------------------
__global__ __launch_bounds__(256, 2) void fuse_cls_kernel(
    const float* __restrict__ out_b, const float* __restrict__ out_c,
    const unsigned short* __restrict__ WfT, const float* __restrict__ bf,
    const float* __restrict__ Wc, float* __restrict__ out)
{
    __shared__ __align__(16) char As[32 * 1024];  // [32 rows][512 bf16], swizzled, 32KB
    __shared__ __align__(16) char Ws[2][16384];   // [256 rows][32 bf16] x2

    const int t = threadIdx.x;
    const int w = t >> 6, l = t & 63;
    const int lr = l & 15, lk = l >> 4;
    const int base = blockIdx.x * 32;
    const int half = blockIdx.y;
    const int colbase = half * 256 + w * 64;
    const unsigned short* wfp = WfT + (size_t)half * 256 * 512;

    const int wrow_l = l >> 2;
    const int wp = l & 3;
    auto stage_w = [&](int kc, int buf) {
#pragma unroll
        for (int s2 = 0; s2 < 4; ++s2) {
            const int row = w * 64 + s2 * 16 + wrow_l;
            const int lslot = wp ^ ((row >> 1) & 3);
            gload_lds16(wfp + (size_t)row * 512 + kc * 32 + lslot * 8,
                        &Ws[buf][w * 4096 + s2 * 1024]);
        }
    };

    stage_w(0, 0);   // issue W(0) first: latency overlaps A staging

    // ---- A stage: 32x512 f32 -> bf16 LDS (once). thread: row t>>3, 64 cols ----
    {
        const int r = t >> 3;
        const int c0 = (t & 7) * 64;
        const float* srcb = (c0 < 256) ? (out_b + (size_t)(base + r) * 256 + c0)
                                       : (out_c + (size_t)(base + r) * 256 + (c0 - 256));
#pragma unroll
        for (int q = 0; q < 8; ++q) {
            const float4 f0 = *(const float4*)(srcb + q * 8);
            const float4 f1 = *(const float4*)(srcb + q * 8 + 4);
            bf16x8 p;
            p[0] = (short)f2bf(f0.x); p[1] = (short)f2bf(f0.y);
            p[2] = (short)f2bf(f0.z); p[3] = (short)f2bf(f0.w);
            p[4] = (short)f2bf(f1.x); p[5] = (short)f2bf(f1.y);
            p[6] = (short)f2bf(f1.z); p[7] = (short)f2bf(f1.w);
            const int s = (t & 7) * 8 + q;   // logical 16B slot [0,64)
            *(bf16x8*)&As[swAs(r, s)] = p;
        }
    }
    LGKMCNT0;

    f32x4 acc[2][4];
#pragma unroll
    for (int mi = 0; mi < 2; ++mi)
#pragma unroll
        for (int nj = 0; nj < 4; ++nj) { f32x4 z = {0.f,0.f,0.f,0.f}; acc[mi][nj] = z; }

    int cur = 0;
#pragma unroll
    for (int kc = 0; kc < 16; ++kc) {
        const int nb = cur ^ 1;
        if (kc < 15) { stage_w(kc + 1, nb); VMCNT(4); }
        else         { VMCNT(0); }
        BARRIER();
        bf16x8 a[2], b[4];
#pragma unroll
        for (int mi = 0; mi < 2; ++mi)
            a[mi] = *(const bf16x8*)&As[swAs(mi * 16 + lr, kc * 4 + lk)];
#pragma unroll
        for (int nj = 0; nj < 4; ++nj)
            b[nj] = *(const bf16x8*)&Ws[cur][sw64(w * 64 + nj * 16 + lr, lk)];
#pragma unroll
        for (int mi = 0; mi < 2; ++mi)
#pragma unroll
            for (int nj = 0; nj < 4; ++nj)
                acc[mi][nj] = __builtin_amdgcn_mfma_f32_16x16x32_bf16(a[mi], b[nj], acc[mi][nj], 0, 0, 0);
        BARRIER();
        cur = nb;
    }

    // epilogue: +bf, relu, x Wc, 16-lane reduce, atomic into out
#pragma unroll
    for (int mi = 0; mi < 2; ++mi)
#pragma unroll
        for (int j = 0; j < 4; ++j) {
            float p0 = 0.f, p1 = 0.f;
#pragma unroll
            for (int nj = 0; nj < 4; ++nj) {
                const int col = colbase + nj * 16 + lr;
                const float r = fmaxf(acc[mi][nj][j] + bf[col], 0.f);
                p0 = fmaf(r, Wc[col * 2 + 0], p0);
                p1 = fmaf(r, Wc[col * 2 + 1], p1);
            }
#pragma unroll
            for (int off = 1; off < 16; off <<= 1) {
                p0 += __shfl_xor(p0, off, 64);
                p1 += __shfl_xor(p1, off, 64);
            }
            if (lr == 0) {
                const int row = base + mi * 16 + lk * 4 + j;
                atomicAdd(&out[row * 2 + 0], p0);
                atomicAdd(&out[row * 2 + 1], p1);
            }
        }
}

// ---------------------------------------------------------------------------
// Losses (unchanged).
// ---------------------------------------------------------------------------
__global__ __launch_bounds__(256) void loss_kernel(
    const float* __restrict__ gsum, const float* __restrict__ cnt,
    const float* __restrict__ sum_out, float* __restrict__ dout)
{
    __shared__ float avg[M_EXP][O_DIM];
    __shared__ float rho_s[M_EXP];
    __shared__ float simv[28];
    __shared__ float prs[28];
    const int t = threadIdx.x;
    if (t < M_EXP) rho_s[t] = cnt[t] + 2.f * cnt[M_EXP + t];
    __syncthreads();
    for (int idx = t; idx < M_EXP * O_DIM; idx += 256) {
        const int m = idx >> 8;
        avg[m][idx & 255] = sum_out[idx] / fmaxf(rho_s[m], 1.f);
    }
    __syncthreads();
    if (t < 28) {
        int a = 0, p = t;
        while (p >= 7 - a) { p -= 7 - a; ++a; }
        const int b = a + 1 + p;
        float d2 = 0.f;
        for (int o = 0; o < O_DIM; ++o) {
            const float df = avg[a][o] - avg[b][o];
            d2 = fmaf(df, df, d2);
        }
        const bool pr = (rho_s[a] > 0.f) && (rho_s[b] > 0.f);
        simv[t] = pr ? expf(-0.5f * d2) : 0.f;
        prs[t]  = pr ? 1.f : 0.f;
    }
    __syncthreads();
    if (t == 0) {
        float s = 0.f, np = 0.f;
        for (int p = 0; p < 28; ++p) { s += simv[p]; np += prs[p]; }
        dout[N_TOK * 2 + 0] = -s / fmaxf(np, 1.f);
        float eq = 0.f;
        for (int m = 0; m < M_EXP; ++m) {
            const float rho = cnt[m] + 2.f * cnt[M_EXP + m];
            const float rh  = gsum[m] + 2.f * gsum[M_EXP + m];
            eq = fmaf(rho, rh, eq);
        }
        dout[N_TOK * 2 + 1] = eq / (float)M_EXP;
    }
}

// ---------------------------------------------------------------------------
extern "C" void kernel_launch(void* const* d_in, const int* in_sizes, int n_in,
                              void* d_out, int out_size, void* d_ws, size_t ws_size,
                              hipStream_t stream)
{
    const float* Xb = (const float*)d_in[0];
    const float* Xc = (const float*)d_in[1];
    // d_in[2] (vec_fcg) intentionally unused: reference source bug reuses cfg.
    const float* Wg = (const float*)d_in[3];
    const float* bg = (const float*)d_in[4];
    const float* W1 = (const float*)d_in[5];
    const float* b1 = (const float*)d_in[6];
    const float* W2 = (const float*)d_in[7];
    const float* b2 = (const float*)d_in[8];
    const float* Wf = (const float*)d_in[9];
    const float* bf = (const float*)d_in[10];
    const float* Wc = (const float*)d_in[11];
    const float* bc = (const float*)d_in[12];
    float* out = (float*)d_out;

    float* ws = (float*)d_ws;
    float* coef_b  = ws;                           // 32768
    float* coef_c  = coef_b + M_EXP * N_TOK;
    float* mask_b  = coef_c + M_EXP * N_TOK;
    float* mask_c  = mask_b + M_EXP * N_TOK;
    float* gsum    = mask_c + M_EXP * N_TOK;       // [2][8]
    float* cnt     = gsum + 16;                    // [2][8]
    float* sum_out = cnt + 16;                     // [8][256]
    float* out_b   = sum_out + M_EXP * O_DIM;      // [4096][256] f32 (atomic)
    float* out_c   = out_b + (size_t)N_TOK * O_DIM;
    unsigned short* W1T = (unsigned short*)(out_c + (size_t)N_TOK * O_DIM); // [8][256][512]
    unsigned short* W2T = W1T + (size_t)M_EXP * H_DIM * D_IN;              // [8][256][256]
    unsigned short* WfT = W2T + (size_t)M_EXP * O_DIM * H_DIM;             // [512][512]
    unsigned short* Xbf = WfT + (size_t)F_DIM * 512;                       // [2][4096][512]

    // zero atomic-accumulated regions (coef..sum_out + out_b + out_c)
    const size_t zero_f = (size_t)(4 * M_EXP * N_TOK + 32 + M_EXP * O_DIM) + 2 * (size_t)N_TOK * O_DIM;
    hipMemsetAsync(d_ws, 0, zero_f * sizeof(float), stream);

    prep_kernel<<<dim3(1824), 256, 0, stream>>>(W1, W2, Wf, bc, W1T, W2T, WfT, out);
    gate_kernel<<<dim3(N_TOK / 4, 2), 256, 0, stream>>>(
        Xb, Xc, Wg, bg, coef_b, coef_c, mask_b, mask_c, gsum, cnt, Xbf);
    expert_mfma_kernel<<<dim3(1024), 256, 0, stream>>>(
        Xbf, W1T, W2T, b1, b2, coef_b, coef_c, mask_b, mask_c, out_b, out_c, sum_out);
    fuse_cls_kernel<<<dim3(N_TOK / 32, 2), 256, 0, stream>>>(out_b, out_c, WfT, bf, Wc, out);
    loss_kernel<<<1, 256, 0, stream>>>(gsum, cnt, sum_out, out);
}

// Round 6
// 98.898 us; speedup vs baseline: 1.6412x; 1.2359x over previous
//
#include <hip/hip_runtime.h>
#include <hip/hip_bf16.h>

// Problem constants: N=4096, D=512, H=256, O=256, M=8, K=2, F=512, C=2
#define N_TOK 4096
#define D_IN  512
#define H_DIM 256
#define O_DIM 256
#define M_EXP 8
#define F_DIM 512

typedef __attribute__((ext_vector_type(8))) short bf16x8;   // 8 bf16 = 4 VGPRs (MFMA A/B frag)
typedef __attribute__((ext_vector_type(4))) float f32x4;    // MFMA C/D frag

#define VMCNT(n)  asm volatile("s_waitcnt vmcnt(" #n ")" ::: "memory")
#define LGKMCNT0  asm volatile("s_waitcnt lgkmcnt(0)" ::: "memory")
#define BARRIER() __builtin_amdgcn_s_barrier()

// RNE f32 -> bf16 bits
__device__ __forceinline__ unsigned short f2bf(float f) {
    unsigned int u = __float_as_uint(f);
    u = (u + 0x7FFFu + ((u >> 16) & 1u)) >> 16;
    return (unsigned short)u;
}

// async global->LDS, 16B per lane; LDS dest wave-uniform base + lane*16
__device__ __forceinline__ void gload_lds16(const void* g, void* l) {
    __builtin_amdgcn_global_load_lds(
        (const __attribute__((address_space(1))) unsigned int*)g,
        (__attribute__((address_space(3))) unsigned int*)l, 16, 0, 0);
}

// Swizzled LDS byte offsets. 64B rows (4x16B slots): slot ^= (row>>1)&3.
__device__ __forceinline__ int sw64(int row, int lslot) {
    return row * 64 + ((lslot ^ ((row >> 1) & 3)) << 4);
}
// 512B rows (32x16B slots): slot ^= row&7.
__device__ __forceinline__ int swHs(int row, int lslot) {
    return row * 512 + ((lslot ^ (row & 7)) << 4);
}
// 1024B rows (64x16B slots): slot ^= row&7.
__device__ __forceinline__ int swAs(int row, int lslot) {
    return row * 1024 + ((lslot ^ (row & 7)) << 4);
}

// ---------------------------------------------------------------------------
// Kernel 1 (merged): weight transposes + WfT fold + out init + zeroing +
// gating. Block ranges:
//   [0,1024)    W1 [8][512][256] -> W1T [8][256][512] bf16
//   [1024,1536) W2 [8][256][256] -> W2T [8][256][256] bf16
//   [1536,1792) WfT_eff[f][j] = Wf[j][f] + (j>=256 ? Wf[j+256][f] : 0)
//   [1792,1824) out init with bc
//   [1824,2336) zero out_b/out_c (8MB)
//   [2336,2337) zero sum_out
//   [2337,4385) gating (f32-exact, reduction order preserved across rounds)
//               + X f32->bf16 (Xbf[2][4096][512]) + FULL coef/mask rows
//               + per-block gate partials (gpart/cpart) -- no global atomics.
// ---------------------------------------------------------------------------
__global__ __launch_bounds__(256) void prep_gate_kernel(
    const float* __restrict__ Xb, const float* __restrict__ Xc,
    const float* __restrict__ Wg, const float* __restrict__ bg,
    const float* __restrict__ W1, const float* __restrict__ W2,
    const float* __restrict__ Wf, const float* __restrict__ bc,
    unsigned short* __restrict__ W1T, unsigned short* __restrict__ W2T,
    unsigned short* __restrict__ WfT, unsigned short* __restrict__ Xbf,
    float* __restrict__ coef_b, float* __restrict__ coef_c,
    float* __restrict__ mask_b, float* __restrict__ mask_c,
    float* __restrict__ gpart, float* __restrict__ cpart,
    float* __restrict__ zero_base, float* __restrict__ sum_out,
    float* __restrict__ out)
{
    __shared__ float tile[32][33];
    __shared__ float s_g[M_EXP];
    __shared__ float s_c[M_EXP];
    const int bx = blockIdx.x;
    const int tr = threadIdx.x >> 3, q = threadIdx.x & 7;

    if (bx < 1024) {            // W1 transpose
        const int e = bx >> 7, tidx = bx & 127;
        const int r0 = (tidx >> 3) * 32, c0 = (tidx & 7) * 32;
        const float* s = W1 + (size_t)e * 512 * 256;
        unsigned short* d = W1T + (size_t)e * 512 * 256;
        *(float4*)&tile[tr][q * 4] = *(const float4*)&s[(size_t)(r0 + tr) * 256 + c0 + q * 4];
        __syncthreads();
        ushort4 o;
        o.x = f2bf(tile[q*4+0][tr]); o.y = f2bf(tile[q*4+1][tr]);
        o.z = f2bf(tile[q*4+2][tr]); o.w = f2bf(tile[q*4+3][tr]);
        *(ushort4*)&d[(size_t)(c0 + tr) * 512 + r0 + q * 4] = o;
    } else if (bx < 1536) {     // W2 transpose
        const int idx = bx - 1024;
        const int e = idx >> 6, tidx = idx & 63;
        const int r0 = (tidx >> 3) * 32, c0 = (tidx & 7) * 32;
        const float* s = W2 + (size_t)e * 256 * 256;
        unsigned short* d = W2T + (size_t)e * 256 * 256;
        *(float4*)&tile[tr][q * 4] = *(const float4*)&s[(size_t)(r0 + tr) * 256 + c0 + q * 4];
        __syncthreads();
        ushort4 o;
        o.x = f2bf(tile[q*4+0][tr]); o.y = f2bf(tile[q*4+1][tr]);
        o.z = f2bf(tile[q*4+2][tr]); o.w = f2bf(tile[q*4+3][tr]);
        *(ushort4*)&d[(size_t)(c0 + tr) * 256 + r0 + q * 4] = o;
    } else if (bx < 1792) {     // Wf fold + transpose
        const int idx = bx - 1536;
        const int j0 = (idx >> 4) * 32, f0 = (idx & 15) * 32;
        float4 v = *(const float4*)&Wf[(size_t)(j0 + tr) * F_DIM + f0 + q * 4];
        if (j0 >= 256) {
            const float4 v2 = *(const float4*)&Wf[(size_t)(j0 + tr + 256) * F_DIM + f0 + q * 4];
            v.x += v2.x; v.y += v2.y; v.z += v2.z; v.w += v2.w;
        }
        *(float4*)&tile[tr][q * 4] = v;
        __syncthreads();
        ushort4 o;
        o.x = f2bf(tile[q*4+0][tr]); o.y = f2bf(tile[q*4+1][tr]);
        o.z = f2bf(tile[q*4+2][tr]); o.w = f2bf(tile[q*4+3][tr]);
        *(ushort4*)&WfT[(size_t)(f0 + tr) * 512 + j0 + q * 4] = o;
    } else if (bx < 1824) {     // out init
        const int i = (bx - 1792) * 256 + threadIdx.x;
        out[i] = bc[i & 1];
    } else if (bx < 2336) {     // zero out_b/out_c
        float4 z = {0.f, 0.f, 0.f, 0.f};
        float* p = zero_base + (size_t)(bx - 1824) * 4096 + threadIdx.x * 16;
#pragma unroll
        for (int k = 0; k < 4; ++k) *(float4*)(p + k * 4) = z;
    } else if (bx < 2337) {     // zero sum_out
#pragma unroll
        for (int k = 0; k < 8; ++k) sum_out[threadIdx.x * 8 + k] = 0.f;
    } else {                    // ---------------- gating ----------------
        const int idx = bx - 2337;
        const int mod = idx >> 10;
        const int b = idx & 1023;
        const float* X = mod ? Xc : Xb;
        float* coef = mod ? coef_c : coef_b;
        float* mask = mod ? mask_c : mask_b;
        const int wave = threadIdx.x >> 6;
        const int lane = threadIdx.x & 63;
        const int n = b * 4 + wave;

        if (threadIdx.x < M_EXP) { s_g[threadIdx.x] = 0.f; s_c[threadIdx.x] = 0.f; }
        __syncthreads();

        float acc[M_EXP] = {0.f,0.f,0.f,0.f,0.f,0.f,0.f,0.f};
        const float* xrow = X + (size_t)n * D_IN;
        unsigned short* xb = Xbf + (size_t)mod * N_TOK * D_IN + (size_t)n * D_IN;
#pragma unroll
        for (int k = 0; k < 8; ++k) {
            const int d = lane + 64 * k;
            const float xv = xrow[d];
            xb[d] = f2bf(xv);
            const float* wr = Wg + d * M_EXP;
#pragma unroll
            for (int m = 0; m < M_EXP; ++m) acc[m] += xv * wr[m];
        }
#pragma unroll
        for (int off = 1; off < 64; off <<= 1) {
#pragma unroll
            for (int m = 0; m < M_EXP; ++m) acc[m] += __shfl_xor(acc[m], off, 64);
        }
        float g[M_EXP];
        float mx = -1e30f;
#pragma unroll
        for (int m = 0; m < M_EXP; ++m) { g[m] = acc[m] + bg[m]; mx = fmaxf(mx, g[m]); }
        float es = 0.f;
#pragma unroll
        for (int m = 0; m < M_EXP; ++m) { g[m] = expf(g[m] - mx); es += g[m]; }
        const float inv = 1.f / es;
#pragma unroll
        for (int m = 0; m < M_EXP; ++m) g[m] *= inv;

        int i0 = 0; float v0 = g[0];
#pragma unroll
        for (int m = 1; m < M_EXP; ++m) if (g[m] > v0) { v0 = g[m]; i0 = m; }
        int i1 = -1; float v1 = -1e30f;
#pragma unroll
        for (int m = 0; m < M_EXP; ++m) if (m != i0 && g[m] > v1) { v1 = g[m]; i1 = m; }

        if (lane == 0) {
            const float wn = 1.f / (v0 + v1);
#pragma unroll
            for (int m = 0; m < M_EXP; ++m) {   // FULL row write -> no memset needed
                const float cv = (m == i0) ? v0 * wn : (m == i1) ? v1 * wn : 0.f;
                coef[m * N_TOK + n] = cv;
                mask[m * N_TOK + n] = (m == i0 || m == i1) ? 1.f : 0.f;
            }
#pragma unroll
            for (int m = 0; m < M_EXP; ++m) atomicAdd(&s_g[m], g[m]);
            atomicAdd(&s_c[i0], 1.f);
            atomicAdd(&s_c[i1], 1.f);
        }
        __syncthreads();
        if (threadIdx.x < M_EXP) {              // per-block partials
            gpart[idx * M_EXP + threadIdx.x] = s_g[threadIdx.x];
            cpart[idx * M_EXP + threadIdx.x] = s_c[threadIdx.x];
        }
    }
}

// ---------------------------------------------------------------------------
// Expert MLPs. One block = expert m x 128 tokens (rows 0-63 binary tile,
// 64-127 cfg tile) -> weights staged ONCE for both modalities. 8 waves
// (2 row-blocks x 4 col-blocks of 64). Triple-buffered Xs/Ws, depth-2
// counted-vmcnt pipeline, ONE s_barrier per K-chunk:
//   VMCNT(n) -> barrier -> stage(c+2) -> ds_read(c) -> 16 MFMA.
// XCD swizzle: xcd=bid&7 owns tiles [xcd*8,xcd*8+8) x all 8 experts ->
// per-XCD working set = 1MB X + 3MB weights ~= L2-resident.
// LDS: Xs 3x8KB + Ws 3x16KB + Hs 64KB = 136KB (1 block/CU).
// ---------------------------------------------------------------------------
__global__ __launch_bounds__(512, 1) void expert_mfma_kernel(
    const unsigned short* __restrict__ Xbf,
    const unsigned short* __restrict__ W1T, const unsigned short* __restrict__ W2T,
    const float* __restrict__ b1, const float* __restrict__ b2,
    const float* __restrict__ coef_b, const float* __restrict__ coef_c,
    const float* __restrict__ mask_b, const float* __restrict__ mask_c,
    float* __restrict__ out_b, float* __restrict__ out_c,
    float* __restrict__ sum_out)
{
    __shared__ __align__(16) char Xs[3][8192];    // [128 rows][32 bf16] x3
    __shared__ __align__(16) char Ws[3][16384];   // [256 rows][32 bf16] x3
    __shared__ __align__(16) char Hs[65536];      // [128 rows][256 bf16]

    const int t = threadIdx.x;
    const int w = t >> 6, l = t & 63;
    const int lr = l & 15, lk = l >> 4;
    const int wr = w >> 2, wc = w & 3;            // 2x4 wave grid

    const int bid = blockIdx.x;
    const int m    = (bid >> 3) & 7;
    const int tile = (bid & 7) * 8 + (bid >> 6);  // tile-group per XCD
    const int base = tile * 64;
    const int wcol = wc * 64;
    const int wrow = wr * 64;

    const unsigned short* w1p = W1T + (size_t)m * H_DIM * D_IN;
    const unsigned short* w2p = W2T + (size_t)m * O_DIM * H_DIM;

    // bias preload, drained BEFORE pipeline (keeps vmcnt counting exact)
    float bv1[4], bv2[4];
#pragma unroll
    for (int nj = 0; nj < 4; ++nj) {
        bv1[nj] = b1[m * H_DIM + wcol + nj * 16 + lr];
        bv2[nj] = b2[m * O_DIM + wcol + nj * 16 + lr];
    }
    VMCNT(0);
#pragma unroll
    for (int nj = 0; nj < 4; ++nj)
        asm volatile("" :: "v"(bv1[nj]), "v"(bv2[nj]));

    // staging geometry (pre-swizzled global source, linear LDS dest)
    const int xr  = t >> 2;                           // 0..127
    const int xls = (t & 3) ^ ((xr >> 1) & 3);
    const unsigned short* xsrc = Xbf
        + (size_t)(xr < 64 ? 0 : 1) * N_TOK * D_IN
        + (size_t)(base + (xr & 63)) * D_IN + xls * 8;
    const int wrl = l >> 2;                           // 0..15
    const int wp  = l & 3;

    auto stage_x = [&](int s) {   // 8KB: 1 gload/wave
        gload_lds16(xsrc + s * 32, &Xs[s % 3][w * 1024]);
    };
    auto stage_w = [&](const unsigned short* wbase, int rowlen, int kc, int s) {
#pragma unroll
        for (int s2 = 0; s2 < 2; ++s2) {              // 16KB: 2 gloads/wave
            const int row = w * 32 + s2 * 16 + wrl;
            const int lslot = wp ^ ((row >> 1) & 3);
            gload_lds16(wbase + (size_t)row * rowlen + kc * 32 + lslot * 8,
                        &Ws[s % 3][w * 2048 + s2 * 1024]);
        }
    };
    auto stage = [&](int s) {     // ops/wave: 3 if s<16, else 2
        if (s < 16) { stage_x(s); stage_w(w1p, 512, s, s); }
        else        { stage_w(w2p, 256, s - 16, s); }
    };

    f32x4 acc[4][4];
#pragma unroll
    for (int mi = 0; mi < 4; ++mi)
#pragma unroll
        for (int nj = 0; nj < 4; ++nj) { f32x4 z = {0.f,0.f,0.f,0.f}; acc[mi][nj] = z; }

    stage(0);
    stage(1);

    // 24 unified chunks: c<16 = h phase (A from Xs), c>=16 = y phase (A from Hs)
#pragma unroll
    for (int c = 0; c < 24; ++c) {
        // need stage(c) landed; outstanding <= ops(c+1)
        if (c <= 14)      VMCNT(3);
        else if (c <= 22) VMCNT(2);
        else              VMCNT(0);
        BARRIER();
        if (c + 2 < 24) stage(c + 2);   // buffer (c+2)%3 == (c-1)%3: reads done at barrier

        bf16x8 a[4], b[4];
        if (c < 16) {
#pragma unroll
            for (int mi = 0; mi < 4; ++mi)
                a[mi] = *(const bf16x8*)&Xs[c % 3][sw64(wrow + mi * 16 + lr, lk)];
        } else {
#pragma unroll
            for (int mi = 0; mi < 4; ++mi)
                a[mi] = *(const bf16x8*)&Hs[swHs(wrow + mi * 16 + lr, (c - 16) * 4 + lk)];
        }
#pragma unroll
        for (int nj = 0; nj < 4; ++nj)
            b[nj] = *(const bf16x8*)&Ws[c % 3][sw64(wcol + nj * 16 + lr, lk)];
#pragma unroll
        for (int mi = 0; mi < 4; ++mi)
#pragma unroll
            for (int nj = 0; nj < 4; ++nj)
                acc[mi][nj] = __builtin_amdgcn_mfma_f32_16x16x32_bf16(a[mi], b[nj], acc[mi][nj], 0, 0, 0);

        if (c == 15) {
            // h = relu(acc + b1) -> Hs (bf16, swizzled); re-zero acc for y
#pragma unroll
            for (int mi = 0; mi < 4; ++mi)
#pragma unroll
                for (int nj = 0; nj < 4; ++nj) {
                    const int col = wcol + nj * 16 + lr;
                    const int cslot = col >> 3;
                    const int cbyte = (col & 7) * 2;
#pragma unroll
                    for (int j = 0; j < 4; ++j) {
                        const int row = wrow + mi * 16 + lk * 4 + j;
                        *(unsigned short*)&Hs[row * 512 + ((cslot ^ (row & 7)) << 4) + cbyte] =
                            f2bf(fmaxf(acc[mi][nj][j] + bv1[nj], 0.f));
                    }
                }
#pragma unroll
            for (int mi = 0; mi < 4; ++mi)
#pragma unroll
                for (int nj = 0; nj < 4; ++nj) { f32x4 z = {0.f,0.f,0.f,0.f}; acc[mi][nj] = z; }
            LGKMCNT0;   // Hs writes retired; published at next chunk's barrier
        }
    }

    // ============ epilogue: top-k combine + masked column sums ============
    const float* coef = wr ? coef_c : coef_b;
    const float* mask = wr ? mask_c : mask_b;
    float* outp = wr ? out_c : out_b;
    const float modw = wr ? 2.f : 1.f;

    float sacc[4] = {0.f, 0.f, 0.f, 0.f};
#pragma unroll
    for (int mi = 0; mi < 4; ++mi)
#pragma unroll
        for (int j = 0; j < 4; ++j) {
            const int lrow = mi * 16 + lk * 4 + j;          // 0..63 within modality
            const float cf = coef[(size_t)m * N_TOK + base + lrow];
            const float mk = mask[(size_t)m * N_TOK + base + lrow];
            const size_t grow = (size_t)(base + lrow) * O_DIM;
#pragma unroll
            for (int nj = 0; nj < 4; ++nj) {
                const float v = acc[mi][nj][j] + bv2[nj];
                if (cf != 0.f) atomicAdd(&outp[grow + wcol + nj * 16 + lr], cf * v);
                sacc[nj] = fmaf(mk, v, sacc[nj]);
            }
        }
#pragma unroll
    for (int nj = 0; nj < 4; ++nj) {
        sacc[nj] += __shfl_xor(sacc[nj], 16, 64);
        sacc[nj] += __shfl_xor(sacc[nj], 32, 64);
    }
    if (lk == 0) {
#pragma unroll
        for (int nj = 0; nj < 4; ++nj)
            atomicAdd(&sum_out[m * O_DIM + wcol + nj * 16 + lr], sacc[nj] * modw);
    }
}

// ---------------------------------------------------------------------------
// Kernel 3: fusion + classifier (grid x<128) + losses (block x==128,y==0).
// Fusion: A-tile 32x512 ([out_b|out_c] bf16 in LDS once); W double-buffered
// counted vmcnt. Loss block: reduce gate partials -> rho/rho_hat, then
// eq_loss + distinctiveness.
// ---------------------------------------------------------------------------
__global__ __launch_bounds__(256, 2) void fuse_cls_loss_kernel(
    const float* __restrict__ out_b, const float* __restrict__ out_c,
    const unsigned short* __restrict__ WfT, const float* __restrict__ bf,
    const float* __restrict__ Wc,
    const float* __restrict__ gpart, const float* __restrict__ cpart,
    const float* __restrict__ sum_out, float* __restrict__ out)
{
    __shared__ __align__(16) char As[32 * 1024];  // [32 rows][512 bf16], swizzled
    __shared__ __align__(16) char Ws[2][16384];   // [256 rows][32 bf16] x2
    __shared__ float avg[M_EXP][O_DIM];
    __shared__ float partl[256];
    __shared__ float rho_s[M_EXP], rhohat_s[M_EXP];
    __shared__ float simv[28], prs[28];

    const int t = threadIdx.x;

    if (blockIdx.x == 128) {                       // ---------- loss ----------
        if (blockIdx.y != 0) return;
        const int e = t & 7, grp = t >> 3;
        float sg = 0.f, sc = 0.f;
        for (int b2 = grp * 64; b2 < grp * 64 + 64; ++b2) {
            const float wgt = (b2 < 1024) ? 1.f : 2.f;
            sg += wgt * gpart[b2 * 8 + e];
            sc += wgt * cpart[b2 * 8 + e];
        }
        partl[t] = sg; __syncthreads();
        if (t < 8) { float s = 0.f; for (int g2 = 0; g2 < 32; ++g2) s += partl[t + 8 * g2]; rhohat_s[t] = s; }
        __syncthreads();
        partl[t] = sc; __syncthreads();
        if (t < 8) { float s = 0.f; for (int g2 = 0; g2 < 32; ++g2) s += partl[t + 8 * g2]; rho_s[t] = s; }
        __syncthreads();
        for (int idx = t; idx < M_EXP * O_DIM; idx += 256)
            avg[idx >> 8][idx & 255] = sum_out[idx] / fmaxf(rho_s[idx >> 8], 1.f);
        __syncthreads();
        if (t < 28) {
            int a = 0, p = t;
            while (p >= 7 - a) { p -= 7 - a; ++a; }
            const int b = a + 1 + p;
            float d2 = 0.f;
            for (int o = 0; o < O_DIM; ++o) {
                const float df = avg[a][o] - avg[b][o];
                d2 = fmaf(df, df, d2);
            }
            const bool pr = (rho_s[a] > 0.f) && (rho_s[b] > 0.f);
            simv[t] = pr ? expf(-0.5f * d2) : 0.f;
            prs[t]  = pr ? 1.f : 0.f;
        }
        __syncthreads();
        if (t == 0) {
            float s = 0.f, np = 0.f;
            for (int p = 0; p < 28; ++p) { s += simv[p]; np += prs[p]; }
            out[N_TOK * 2 + 0] = -s / fmaxf(np, 1.f);
            float eq = 0.f;
            for (int m = 0; m < M_EXP; ++m) eq = fmaf(rho_s[m], rhohat_s[m], eq);
            out[N_TOK * 2 + 1] = eq / (float)M_EXP;
        }
        return;
    }

    // ---------- fusion + classifier ----------
    const int w = t >> 6, l = t & 63;
    const int lr = l & 15, lk = l >> 4;
    const int base = blockIdx.x * 32;
    const int half = blockIdx.y;
    const int colbase = half * 256 + w * 64;
    const unsigned short* wfp = WfT + (size_t)half * 256 * 512;

    const int wrl = l >> 2;
    const int wp = l & 3;
    auto stage_w = [&](int kc, int buf) {
#pragma unroll
        for (int s2 = 0; s2 < 4; ++s2) {
            const int row = w * 64 + s2 * 16 + wrl;
            const int lslot = wp ^ ((row >> 1) & 3);
            gload_lds16(wfp + (size_t)row * 512 + kc * 32 + lslot * 8,
                        &Ws[buf][w * 4096 + s2 * 1024]);
        }
    };

    stage_w(0, 0);

    {   // A stage: 32x512 f32 -> bf16 LDS (once)
        const int r = t >> 3;
        const int c0 = (t & 7) * 64;
        const float* srcb = (c0 < 256) ? (out_b + (size_t)(base + r) * 256 + c0)
                                       : (out_c + (size_t)(base + r) * 256 + (c0 - 256));
#pragma unroll
        for (int q = 0; q < 8; ++q) {
            const float4 f0 = *(const float4*)(srcb + q * 8);
            const float4 f1 = *(const float4*)(srcb + q * 8 + 4);
            bf16x8 p;
            p[0] = (short)f2bf(f0.x); p[1] = (short)f2bf(f0.y);
            p[2] = (short)f2bf(f0.z); p[3] = (short)f2bf(f0.w);
            p[4] = (short)f2bf(f1.x); p[5] = (short)f2bf(f1.y);
            p[6] = (short)f2bf(f1.z); p[7] = (short)f2bf(f1.w);
            const int s = (t & 7) * 8 + q;
            *(bf16x8*)&As[swAs(r, s)] = p;
        }
    }
    LGKMCNT0;

    f32x4 acc[2][4];
#pragma unroll
    for (int mi = 0; mi < 2; ++mi)
#pragma unroll
        for (int nj = 0; nj < 4; ++nj) { f32x4 z = {0.f,0.f,0.f,0.f}; acc[mi][nj] = z; }

    int cur = 0;
#pragma unroll
    for (int kc = 0; kc < 16; ++kc) {
        const int nb = cur ^ 1;
        if (kc < 15) { stage_w(kc + 1, nb); VMCNT(4); }
        else         { VMCNT(0); }
        BARRIER();
        bf16x8 a[2], b[4];
#pragma unroll
        for (int mi = 0; mi < 2; ++mi)
            a[mi] = *(const bf16x8*)&As[swAs(mi * 16 + lr, kc * 4 + lk)];
#pragma unroll
        for (int nj = 0; nj < 4; ++nj)
            b[nj] = *(const bf16x8*)&Ws[cur][sw64(w * 64 + nj * 16 + lr, lk)];
#pragma unroll
        for (int mi = 0; mi < 2; ++mi)
#pragma unroll
            for (int nj = 0; nj < 4; ++nj)
                acc[mi][nj] = __builtin_amdgcn_mfma_f32_16x16x32_bf16(a[mi], b[nj], acc[mi][nj], 0, 0, 0);
        BARRIER();
        cur = nb;
    }

    // epilogue: +bf, relu, x Wc, 16-lane reduce, atomic into out (bc pre-init)
#pragma unroll
    for (int mi = 0; mi < 2; ++mi)
#pragma unroll
        for (int j = 0; j < 4; ++j) {
            float p0 = 0.f, p1 = 0.f;
#pragma unroll
            for (int nj = 0; nj < 4; ++nj) {
                const int col = colbase + nj * 16 + lr;
                const float r = fmaxf(acc[mi][nj][j] + bf[col], 0.f);
                p0 = fmaf(r, Wc[col * 2 + 0], p0);
                p1 = fmaf(r, Wc[col * 2 + 1], p1);
            }
#pragma unroll
            for (int off = 1; off < 16; off <<= 1) {
                p0 += __shfl_xor(p0, off, 64);
                p1 += __shfl_xor(p1, off, 64);
            }
            if (lr == 0) {
                const int row = base + mi * 16 + lk * 4 + j;
                atomicAdd(&out[row * 2 + 0], p0);
                atomicAdd(&out[row * 2 + 1], p1);
            }
        }
}

// ---------------------------------------------------------------------------
extern "C" void kernel_launch(void* const* d_in, const int* in_sizes, int n_in,
                              void* d_out, int out_size, void* d_ws, size_t ws_size,
                              hipStream_t stream)
{
    const float* Xb = (const float*)d_in[0];
    const float* Xc = (const float*)d_in[1];
    // d_in[2] (vec_fcg) intentionally unused: reference source bug reuses cfg.
    const float* Wg = (const float*)d_in[3];
    const float* bg = (const float*)d_in[4];
    const float* W1 = (const float*)d_in[5];
    const float* b1 = (const float*)d_in[6];
    const float* W2 = (const float*)d_in[7];
    const float* b2 = (const float*)d_in[8];
    const float* Wf = (const float*)d_in[9];
    const float* bf = (const float*)d_in[10];
    const float* Wc = (const float*)d_in[11];
    const float* bc = (const float*)d_in[12];
    float* out = (float*)d_out;

    float* ws = (float*)d_ws;
    float* coef_b  = ws;                            // [8][4096]
    float* coef_c  = coef_b + M_EXP * N_TOK;
    float* mask_b  = coef_c + M_EXP * N_TOK;
    float* mask_c  = mask_b + M_EXP * N_TOK;
    float* gpart   = mask_c + M_EXP * N_TOK;        // [2048][8]
    float* cpart   = gpart + 2048 * M_EXP;          // [2048][8]
    float* sum_out = cpart + 2048 * M_EXP;          // [8][256]
    float* out_b   = sum_out + M_EXP * O_DIM;       // [4096][256] f32 (atomic)
    float* out_c   = out_b + (size_t)N_TOK * O_DIM;
    unsigned short* W1T = (unsigned short*)(out_c + (size_t)N_TOK * O_DIM); // [8][256][512]
    unsigned short* W2T = W1T + (size_t)M_EXP * H_DIM * D_IN;               // [8][256][256]
    unsigned short* WfT = W2T + (size_t)M_EXP * O_DIM * H_DIM;              // [512][512]
    unsigned short* Xbf = WfT + (size_t)F_DIM * 512;                        // [2][4096][512]

    prep_gate_kernel<<<dim3(4385), 256, 0, stream>>>(
        Xb, Xc, Wg, bg, W1, W2, Wf, bc,
        W1T, W2T, WfT, Xbf,
        coef_b, coef_c, mask_b, mask_c, gpart, cpart,
        out_b /*zero base*/, sum_out, out);
    expert_mfma_kernel<<<dim3(512), 512, 0, stream>>>(
        Xbf, W1T, W2T, b1, b2, coef_b, coef_c, mask_b, mask_c, out_b, out_c, sum_out);
    fuse_cls_loss_kernel<<<dim3(129, 2), 256, 0, stream>>>(
        out_b, out_c, WfT, bf, Wc, gpart, cpart, sum_out, out);
}

// Round 7
// 97.889 us; speedup vs baseline: 1.6581x; 1.0103x over previous
//
#include <hip/hip_runtime.h>
#include <hip/hip_bf16.h>

// Problem constants: N=4096, D=512, H=256, O=256, M=8, K=2, F=512, C=2
#define N_TOK 4096
#define D_IN  512
#define H_DIM 256
#define O_DIM 256
#define M_EXP 8
#define F_DIM 512

typedef __attribute__((ext_vector_type(8))) short bf16x8;   // 8 bf16 = 4 VGPRs
typedef __attribute__((ext_vector_type(4))) float f32x4;    // MFMA C/D frag

#define VMCNT(n)  asm volatile("s_waitcnt vmcnt(" #n ")" ::: "memory")
#define LGKMCNT0  asm volatile("s_waitcnt lgkmcnt(0)" ::: "memory")
#define BARRIER() __builtin_amdgcn_s_barrier()

// RNE f32 -> bf16 bits
__device__ __forceinline__ unsigned short f2bf(float f) {
    unsigned int u = __float_as_uint(f);
    u = (u + 0x7FFFu + ((u >> 16) & 1u)) >> 16;
    return (unsigned short)u;
}

// async global->LDS, 16B per lane; LDS dest wave-uniform base + lane*16
__device__ __forceinline__ void gload_lds16(const void* g, void* l) {
    __builtin_amdgcn_global_load_lds(
        (const __attribute__((address_space(1))) unsigned int*)g,
        (__attribute__((address_space(3))) unsigned int*)l, 16, 0, 0);
}

// Swizzled LDS byte offset for [R][32 bf16] tiles (64B rows, 4x16B slots).
__device__ __forceinline__ int sw64(int row, int lslot) {
    return row * 64 + ((lslot ^ ((row >> 1) & 3)) << 4);
}
// 1024B rows (64x16B slots): slot ^= row&7.
__device__ __forceinline__ int swAs(int row, int lslot) {
    return row * 1024 + ((lslot ^ (row & 7)) << 4);
}

// ---------------------------------------------------------------------------
// Kernel 1 (merged): weight transposes + WfT fold + out init + zeroing +
// gating (f32-exact, reduction order preserved) + X f32->bf16.
// ---------------------------------------------------------------------------
__global__ __launch_bounds__(256) void prep_gate_kernel(
    const float* __restrict__ Xb, const float* __restrict__ Xc,
    const float* __restrict__ Wg, const float* __restrict__ bg,
    const float* __restrict__ W1, const float* __restrict__ W2,
    const float* __restrict__ Wf, const float* __restrict__ bc,
    unsigned short* __restrict__ W1T, unsigned short* __restrict__ W2T,
    unsigned short* __restrict__ WfT, unsigned short* __restrict__ Xbf,
    float* __restrict__ coef_b, float* __restrict__ coef_c,
    float* __restrict__ mask_b, float* __restrict__ mask_c,
    float* __restrict__ gpart, float* __restrict__ cpart,
    float* __restrict__ zero_base, float* __restrict__ sum_out,
    float* __restrict__ out)
{
    __shared__ float tile[32][33];
    __shared__ float s_g[M_EXP];
    __shared__ float s_c[M_EXP];
    const int bx = blockIdx.x;
    const int tr = threadIdx.x >> 3, q = threadIdx.x & 7;

    if (bx < 1024) {            // W1 [8][512][256] -> W1T [8][256][512]
        const int e = bx >> 7, tidx = bx & 127;
        const int r0 = (tidx >> 3) * 32, c0 = (tidx & 7) * 32;
        const float* s = W1 + (size_t)e * 512 * 256;
        unsigned short* d = W1T + (size_t)e * 512 * 256;
        *(float4*)&tile[tr][q * 4] = *(const float4*)&s[(size_t)(r0 + tr) * 256 + c0 + q * 4];
        __syncthreads();
        ushort4 o;
        o.x = f2bf(tile[q*4+0][tr]); o.y = f2bf(tile[q*4+1][tr]);
        o.z = f2bf(tile[q*4+2][tr]); o.w = f2bf(tile[q*4+3][tr]);
        *(ushort4*)&d[(size_t)(c0 + tr) * 512 + r0 + q * 4] = o;
    } else if (bx < 1536) {     // W2 [8][256][256] -> W2T [8][256][256]
        const int idx = bx - 1024;
        const int e = idx >> 6, tidx = idx & 63;
        const int r0 = (tidx >> 3) * 32, c0 = (tidx & 7) * 32;
        const float* s = W2 + (size_t)e * 256 * 256;
        unsigned short* d = W2T + (size_t)e * 256 * 256;
        *(float4*)&tile[tr][q * 4] = *(const float4*)&s[(size_t)(r0 + tr) * 256 + c0 + q * 4];
        __syncthreads();
        ushort4 o;
        o.x = f2bf(tile[q*4+0][tr]); o.y = f2bf(tile[q*4+1][tr]);
        o.z = f2bf(tile[q*4+2][tr]); o.w = f2bf(tile[q*4+3][tr]);
        *(ushort4*)&d[(size_t)(c0 + tr) * 256 + r0 + q * 4] = o;
    } else if (bx < 1792) {     // WfT_eff[f][j] = Wf[j][f] + (j>=256 ? Wf[j+256][f] : 0)
        const int idx = bx - 1536;
        const int j0 = (idx >> 4) * 32, f0 = (idx & 15) * 32;
        float4 v = *(const float4*)&Wf[(size_t)(j0 + tr) * F_DIM + f0 + q * 4];
        if (j0 >= 256) {
            const float4 v2 = *(const float4*)&Wf[(size_t)(j0 + tr + 256) * F_DIM + f0 + q * 4];
            v.x += v2.x; v.y += v2.y; v.z += v2.z; v.w += v2.w;
        }
        *(float4*)&tile[tr][q * 4] = v;
        __syncthreads();
        ushort4 o;
        o.x = f2bf(tile[q*4+0][tr]); o.y = f2bf(tile[q*4+1][tr]);
        o.z = f2bf(tile[q*4+2][tr]); o.w = f2bf(tile[q*4+3][tr]);
        *(ushort4*)&WfT[(size_t)(f0 + tr) * 512 + j0 + q * 4] = o;
    } else if (bx < 1824) {     // out init
        const int i = (bx - 1792) * 256 + threadIdx.x;
        out[i] = bc[i & 1];
    } else if (bx < 2336) {     // zero out_b/out_c
        float4 z = {0.f, 0.f, 0.f, 0.f};
        float* p = zero_base + (size_t)(bx - 1824) * 4096 + threadIdx.x * 16;
#pragma unroll
        for (int k = 0; k < 4; ++k) *(float4*)(p + k * 4) = z;
    } else if (bx < 2337) {     // zero sum_out
#pragma unroll
        for (int k = 0; k < 8; ++k) sum_out[threadIdx.x * 8 + k] = 0.f;
    } else {                    // ---------------- gating ----------------
        const int idx = bx - 2337;
        const int mod = idx >> 10;
        const int b = idx & 1023;
        const float* X = mod ? Xc : Xb;
        float* coef = mod ? coef_c : coef_b;
        float* mask = mod ? mask_c : mask_b;
        const int wave = threadIdx.x >> 6;
        const int lane = threadIdx.x & 63;
        const int n = b * 4 + wave;

        if (threadIdx.x < M_EXP) { s_g[threadIdx.x] = 0.f; s_c[threadIdx.x] = 0.f; }
        __syncthreads();

        float acc[M_EXP] = {0.f,0.f,0.f,0.f,0.f,0.f,0.f,0.f};
        const float* xrow = X + (size_t)n * D_IN;
        unsigned short* xb = Xbf + (size_t)mod * N_TOK * D_IN + (size_t)n * D_IN;
#pragma unroll
        for (int k = 0; k < 8; ++k) {
            const int d = lane + 64 * k;
            const float xv = xrow[d];
            xb[d] = f2bf(xv);
            const float* wr = Wg + d * M_EXP;
#pragma unroll
            for (int m = 0; m < M_EXP; ++m) acc[m] += xv * wr[m];
        }
#pragma unroll
        for (int off = 1; off < 64; off <<= 1) {
#pragma unroll
            for (int m = 0; m < M_EXP; ++m) acc[m] += __shfl_xor(acc[m], off, 64);
        }
        float g[M_EXP];
        float mx = -1e30f;
#pragma unroll
        for (int m = 0; m < M_EXP; ++m) { g[m] = acc[m] + bg[m]; mx = fmaxf(mx, g[m]); }
        float es = 0.f;
#pragma unroll
        for (int m = 0; m < M_EXP; ++m) { g[m] = expf(g[m] - mx); es += g[m]; }
        const float inv = 1.f / es;
#pragma unroll
        for (int m = 0; m < M_EXP; ++m) g[m] *= inv;

        int i0 = 0; float v0 = g[0];
#pragma unroll
        for (int m = 1; m < M_EXP; ++m) if (g[m] > v0) { v0 = g[m]; i0 = m; }
        int i1 = -1; float v1 = -1e30f;
#pragma unroll
        for (int m = 0; m < M_EXP; ++m) if (m != i0 && g[m] > v1) { v1 = g[m]; i1 = m; }

        if (lane == 0) {
            const float wn = 1.f / (v0 + v1);
#pragma unroll
            for (int m = 0; m < M_EXP; ++m) {   // FULL row write -> no memset
                const float cv = (m == i0) ? v0 * wn : (m == i1) ? v1 * wn : 0.f;
                coef[m * N_TOK + n] = cv;
                mask[m * N_TOK + n] = (m == i0 || m == i1) ? 1.f : 0.f;
            }
#pragma unroll
            for (int m = 0; m < M_EXP; ++m) atomicAdd(&s_g[m], g[m]);
            atomicAdd(&s_c[i0], 1.f);
            atomicAdd(&s_c[i1], 1.f);
        }
        __syncthreads();
        if (threadIdx.x < M_EXP) {
            gpart[idx * M_EXP + threadIdx.x] = s_g[threadIdx.x];
            cpart[idx * M_EXP + threadIdx.x] = s_c[threadIdx.x];
        }
    }
}

// ---------------------------------------------------------------------------
// h-GEMM (one modality): H = relu(X @ W1_all + b1), viewed as dense
// [4096 x 2048] = [4096 x 512] @ [512 x 2048]. B = W1T flat [2048][512].
// 128x128 tile, 4 waves (2x2 of 64x64), BK=32 -> 16 chunks. Triple-buffered
// counted-vmcnt single-barrier pipeline. LDS 48KB -> 3 blocks/CU
// (inter-block overlap hides latency). Output Hbuf[8][4096][256] bf16 via
// LDS-staged vectorized stores. XCD swizzle: xcd owns 4 row-tiles x all cols.
// ---------------------------------------------------------------------------
__global__ __launch_bounds__(256, 3) void h_gemm_kernel(
    const unsigned short* __restrict__ Xmod,   // [4096][512] bf16
    const unsigned short* __restrict__ W1T,    // flat [2048][512] bf16
    const float* __restrict__ b1,              // flat [2048]
    unsigned short* __restrict__ Hbuf)         // [8][4096][256] bf16
{
    __shared__ __align__(16) char lds[49152];  // A 3x8K @0, B 3x8K @24K; Cs 32K @0

    const int t = threadIdx.x;
    const int w = t >> 6, l = t & 63;
    const int lr = l & 15, lk = l >> 4;
    const int wrow = (w >> 1) * 64, wcol = (w & 1) * 64;

    const int bid = blockIdx.x;                 // 512 blocks
    const int xcd = bid & 7, idx = bid >> 3;    // idx 0..63
    const int rt = xcd * 4 + (idx & 3);         // 0..31
    const int ct = idx >> 2;                    // 0..15
    const int r0 = rt * 128, c0 = ct * 128;

    // bias preload + drain (keeps vmcnt counting exact)
    float bv[4];
#pragma unroll
    for (int nj = 0; nj < 4; ++nj) bv[nj] = b1[c0 + wcol + nj * 16 + lr];
    VMCNT(0);
#pragma unroll
    for (int nj = 0; nj < 4; ++nj) asm volatile("" :: "v"(bv[nj]));

    const int srow = l >> 2;                    // 0..15
    const int sslot = l & 3;

    auto stage = [&](int kc) {                  // 4 gloads/wave
        const int buf = kc % 3;
#pragma unroll
        for (int s = 0; s < 2; ++s) {
            const int row = w * 32 + s * 16 + srow;
            const int lsA = sslot ^ ((row >> 1) & 3);
            gload_lds16(Xmod + (size_t)(r0 + row) * 512 + kc * 32 + lsA * 8,
                        lds + buf * 8192 + w * 2048 + s * 1024);
            gload_lds16(W1T + (size_t)(c0 + row) * 512 + kc * 32 + lsA * 8,
                        lds + 24576 + buf * 8192 + w * 2048 + s * 1024);
        }
    };

    f32x4 acc[4][4];
#pragma unroll
    for (int mi = 0; mi < 4; ++mi)
#pragma unroll
        for (int nj = 0; nj < 4; ++nj) { f32x4 z = {0.f,0.f,0.f,0.f}; acc[mi][nj] = z; }

    stage(0);
    stage(1);
#pragma unroll
    for (int kc = 0; kc < 16; ++kc) {
        if (kc <= 14) { VMCNT(4); } else { VMCNT(0); }
        BARRIER();
        if (kc + 2 < 16) stage(kc + 2);   // into (kc-1)%3: fully consumed last iter
        const char* As = lds + (kc % 3) * 8192;
        const char* Bs = lds + 24576 + (kc % 3) * 8192;
        bf16x8 a[4], b[4];
#pragma unroll
        for (int mi = 0; mi < 4; ++mi)
            a[mi] = *(const bf16x8*)(As + sw64(wrow + mi * 16 + lr, lk));
#pragma unroll
        for (int nj = 0; nj < 4; ++nj)
            b[nj] = *(const bf16x8*)(Bs + sw64(wcol + nj * 16 + lr, lk));
#pragma unroll
        for (int mi = 0; mi < 4; ++mi)
#pragma unroll
            for (int nj = 0; nj < 4; ++nj)
                acc[mi][nj] = __builtin_amdgcn_mfma_f32_16x16x32_bf16(a[mi], b[nj], acc[mi][nj], 0, 0, 0);
    }

    // epilogue: relu(acc+b1) -> bf16 -> LDS Cs [128][128] -> vectorized store
    BARRIER();   // all waves' last-chunk MFMAs consumed their ds_reads
#pragma unroll
    for (int mi = 0; mi < 4; ++mi)
#pragma unroll
        for (int nj = 0; nj < 4; ++nj) {
            const int col = wcol + nj * 16 + lr;
#pragma unroll
            for (int j = 0; j < 4; ++j) {
                const int row = wrow + mi * 16 + lk * 4 + j;
                *(unsigned short*)(lds + row * 256 + col * 2) =
                    f2bf(fmaxf(acc[mi][nj][j] + bv[nj], 0.f));
            }
        }
    LGKMCNT0;
    BARRIER();
    {
        const int e = c0 >> 8, hc0 = c0 & 255;
#pragma unroll
        for (int q2 = 0; q2 < 4; ++q2) {
            const int u = q2 * 512 + t;
            const int row = u >> 4, cs = u & 15;
            *(bf16x8*)(Hbuf + ((size_t)e * 4096 + r0 + row) * 256 + hc0 + cs * 8) =
                *(const bf16x8*)(lds + u * 16);
        }
    }
}

// ---------------------------------------------------------------------------
// y-GEMM (one modality), grouped per expert: Y_e = Hbuf[e] @ W2[e] + b2[e].
// 128x128 tile, K=256 -> 8 chunks, same pipeline. Epilogue: top-k combine
// (predicated f32 atomics into out) + masked column sums -> sum_out.
// ---------------------------------------------------------------------------
__global__ __launch_bounds__(256, 3) void y_gemm_kernel(
    const unsigned short* __restrict__ Hbuf,   // [8][4096][256] bf16
    const unsigned short* __restrict__ W2T,    // [8][256][256] bf16
    const float* __restrict__ b2,              // [8][256]
    const float* __restrict__ coef, const float* __restrict__ mask,
    float* __restrict__ outp, float* __restrict__ sum_out, float modw)
{
    __shared__ __align__(16) char lds[49152];

    const int t = threadIdx.x;
    const int w = t >> 6, l = t & 63;
    const int lr = l & 15, lk = l >> 4;
    const int wrow = (w >> 1) * 64, wcol = (w & 1) * 64;

    const int bid = blockIdx.x;                 // 512 blocks
    const int xcd = bid & 7, idx = bid >> 3;    // idx 0..63
    const int e  = idx >> 3;                    // 0..7
    const int mt = xcd * 4 + ((idx >> 1) & 3);  // 0..31
    const int nt = idx & 1;
    const int r0 = mt * 128, oc0 = nt * 128;

    const unsigned short* Amod = Hbuf + (size_t)e * 4096 * 256;
    const unsigned short* Bmod = W2T + (size_t)e * 256 * 256;

    float bv[4];
#pragma unroll
    for (int nj = 0; nj < 4; ++nj) bv[nj] = b2[e * 256 + oc0 + wcol + nj * 16 + lr];
    VMCNT(0);
#pragma unroll
    for (int nj = 0; nj < 4; ++nj) asm volatile("" :: "v"(bv[nj]));

    const int srow = l >> 2;
    const int sslot = l & 3;

    auto stage = [&](int kc) {
        const int buf = kc % 3;
#pragma unroll
        for (int s = 0; s < 2; ++s) {
            const int row = w * 32 + s * 16 + srow;
            const int lsA = sslot ^ ((row >> 1) & 3);
            gload_lds16(Amod + (size_t)(r0 + row) * 256 + kc * 32 + lsA * 8,
                        lds + buf * 8192 + w * 2048 + s * 1024);
            gload_lds16(Bmod + (size_t)(oc0 + row) * 256 + kc * 32 + lsA * 8,
                        lds + 24576 + buf * 8192 + w * 2048 + s * 1024);
        }
    };

    f32x4 acc[4][4];
#pragma unroll
    for (int mi = 0; mi < 4; ++mi)
#pragma unroll
        for (int nj = 0; nj < 4; ++nj) { f32x4 z = {0.f,0.f,0.f,0.f}; acc[mi][nj] = z; }

    stage(0);
    stage(1);
#pragma unroll
    for (int kc = 0; kc < 8; ++kc) {
        if (kc <= 6) { VMCNT(4); } else { VMCNT(0); }
        BARRIER();
        if (kc + 2 < 8) stage(kc + 2);
        const char* As = lds + (kc % 3) * 8192;
        const char* Bs = lds + 24576 + (kc % 3) * 8192;
        bf16x8 a[4], b[4];
#pragma unroll
        for (int mi = 0; mi < 4; ++mi)
            a[mi] = *(const bf16x8*)(As + sw64(wrow + mi * 16 + lr, lk));
#pragma unroll
        for (int nj = 0; nj < 4; ++nj)
            b[nj] = *(const bf16x8*)(Bs + sw64(wcol + nj * 16 + lr, lk));
#pragma unroll
        for (int mi = 0; mi < 4; ++mi)
#pragma unroll
            for (int nj = 0; nj < 4; ++nj)
                acc[mi][nj] = __builtin_amdgcn_mfma_f32_16x16x32_bf16(a[mi], b[nj], acc[mi][nj], 0, 0, 0);
    }

    // epilogue: top-k combine + masked column sums
    float sacc[4] = {0.f, 0.f, 0.f, 0.f};
#pragma unroll
    for (int mi = 0; mi < 4; ++mi)
#pragma unroll
        for (int j = 0; j < 4; ++j) {
            const int n = r0 + wrow + mi * 16 + lk * 4 + j;
            const float cf = coef[(size_t)e * N_TOK + n];
            const float mk = mask[(size_t)e * N_TOK + n];
            const size_t grow = (size_t)n * O_DIM;
#pragma unroll
            for (int nj = 0; nj < 4; ++nj) {
                const float v = acc[mi][nj][j] + bv[nj];
                const int col = oc0 + wcol + nj * 16 + lr;
                if (cf != 0.f) atomicAdd(&outp[grow + col], cf * v);
                sacc[nj] = fmaf(mk, v, sacc[nj]);
            }
        }
#pragma unroll
    for (int nj = 0; nj < 4; ++nj) {
        sacc[nj] += __shfl_xor(sacc[nj], 16, 64);
        sacc[nj] += __shfl_xor(sacc[nj], 32, 64);
    }
    if (lk == 0) {
#pragma unroll
        for (int nj = 0; nj < 4; ++nj)
            atomicAdd(&sum_out[e * O_DIM + oc0 + wcol + nj * 16 + lr], sacc[nj] * modw);
    }
}

// ---------------------------------------------------------------------------
// Fusion + classifier (x<128) + losses (block x==128,y==0). Unchanged from r6.
// ---------------------------------------------------------------------------
__global__ __launch_bounds__(256, 2) void fuse_cls_loss_kernel(
    const float* __restrict__ out_b, const float* __restrict__ out_c,
    const unsigned short* __restrict__ WfT, const float* __restrict__ bf,
    const float* __restrict__ Wc,
    const float* __restrict__ gpart, const float* __restrict__ cpart,
    const float* __restrict__ sum_out, float* __restrict__ out)
{
    __shared__ __align__(16) char As[32 * 1024];
    __shared__ __align__(16) char Ws[2][16384];
    __shared__ float avg[M_EXP][O_DIM];
    __shared__ float partl[256];
    __shared__ float rho_s[M_EXP], rhohat_s[M_EXP];
    __shared__ float simv[28], prs[28];

    const int t = threadIdx.x;

    if (blockIdx.x == 128) {                       // ---------- loss ----------
        if (blockIdx.y != 0) return;
        const int e = t & 7, grp = t >> 3;
        float sg = 0.f, sc = 0.f;
        for (int b2 = grp * 64; b2 < grp * 64 + 64; ++b2) {
            const float wgt = (b2 < 1024) ? 1.f : 2.f;
            sg += wgt * gpart[b2 * 8 + e];
            sc += wgt * cpart[b2 * 8 + e];
        }
        partl[t] = sg; __syncthreads();
        if (t < 8) { float s = 0.f; for (int g2 = 0; g2 < 32; ++g2) s += partl[t + 8 * g2]; rhohat_s[t] = s; }
        __syncthreads();
        partl[t] = sc; __syncthreads();
        if (t < 8) { float s = 0.f; for (int g2 = 0; g2 < 32; ++g2) s += partl[t + 8 * g2]; rho_s[t] = s; }
        __syncthreads();
        for (int idx = t; idx < M_EXP * O_DIM; idx += 256)
            avg[idx >> 8][idx & 255] = sum_out[idx] / fmaxf(rho_s[idx >> 8], 1.f);
        __syncthreads();
        if (t < 28) {
            int a = 0, p = t;
            while (p >= 7 - a) { p -= 7 - a; ++a; }
            const int b = a + 1 + p;
            float d2 = 0.f;
            for (int o = 0; o < O_DIM; ++o) {
                const float df = avg[a][o] - avg[b][o];
                d2 = fmaf(df, df, d2);
            }
            const bool pr = (rho_s[a] > 0.f) && (rho_s[b] > 0.f);
            simv[t] = pr ? expf(-0.5f * d2) : 0.f;
            prs[t]  = pr ? 1.f : 0.f;
        }
        __syncthreads();
        if (t == 0) {
            float s = 0.f, np = 0.f;
            for (int p = 0; p < 28; ++p) { s += simv[p]; np += prs[p]; }
            out[N_TOK * 2 + 0] = -s / fmaxf(np, 1.f);
            float eq = 0.f;
            for (int m = 0; m < M_EXP; ++m) eq = fmaf(rho_s[m], rhohat_s[m], eq);
            out[N_TOK * 2 + 1] = eq / (float)M_EXP;
        }
        return;
    }

    // ---------- fusion + classifier ----------
    const int w = t >> 6, l = t & 63;
    const int lr = l & 15, lk = l >> 4;
    const int base = blockIdx.x * 32;
    const int half = blockIdx.y;
    const int colbase = half * 256 + w * 64;
    const unsigned short* wfp = WfT + (size_t)half * 256 * 512;

    const int wrl = l >> 2;
    const int wp = l & 3;
    auto stage_w = [&](int kc, int buf) {
#pragma unroll
        for (int s2 = 0; s2 < 4; ++s2) {
            const int row = w * 64 + s2 * 16 + wrl;
            const int lslot = wp ^ ((row >> 1) & 3);
            gload_lds16(wfp + (size_t)row * 512 + kc * 32 + lslot * 8,
                        &Ws[buf][w * 4096 + s2 * 1024]);
        }
    };

    stage_w(0, 0);

    {   // A stage: 32x512 f32 -> bf16 LDS (once)
        const int r = t >> 3;
        const int c0 = (t & 7) * 64;
        const float* srcb = (c0 < 256) ? (out_b + (size_t)(base + r) * 256 + c0)
                                       : (out_c + (size_t)(base + r) * 256 + (c0 - 256));
#pragma unroll
        for (int q = 0; q < 8; ++q) {
            const float4 f0 = *(const float4*)(srcb + q * 8);
            const float4 f1 = *(const float4*)(srcb + q * 8 + 4);
            bf16x8 p;
            p[0] = (short)f2bf(f0.x); p[1] = (short)f2bf(f0.y);
            p[2] = (short)f2bf(f0.z); p[3] = (short)f2bf(f0.w);
            p[4] = (short)f2bf(f1.x); p[5] = (short)f2bf(f1.y);
            p[6] = (short)f2bf(f1.z); p[7] = (short)f2bf(f1.w);
            const int s = (t & 7) * 8 + q;
            *(bf16x8*)&As[swAs(r, s)] = p;
        }
    }
    LGKMCNT0;

    f32x4 acc[2][4];
#pragma unroll
    for (int mi = 0; mi < 2; ++mi)
#pragma unroll
        for (int nj = 0; nj < 4; ++nj) { f32x4 z = {0.f,0.f,0.f,0.f}; acc[mi][nj] = z; }

    int cur = 0;
#pragma unroll
    for (int kc = 0; kc < 16; ++kc) {
        const int nb = cur ^ 1;
        if (kc < 15) { stage_w(kc + 1, nb); VMCNT(4); }
        else         { VMCNT(0); }
        BARRIER();
        bf16x8 a[2], b[4];
#pragma unroll
        for (int mi = 0; mi < 2; ++mi)
            a[mi] = *(const bf16x8*)&As[swAs(mi * 16 + lr, kc * 4 + lk)];
#pragma unroll
        for (int nj = 0; nj < 4; ++nj)
            b[nj] = *(const bf16x8*)&Ws[cur][sw64(w * 64 + nj * 16 + lr, lk)];
#pragma unroll
        for (int mi = 0; mi < 2; ++mi)
#pragma unroll
            for (int nj = 0; nj < 4; ++nj)
                acc[mi][nj] = __builtin_amdgcn_mfma_f32_16x16x32_bf16(a[mi], b[nj], acc[mi][nj], 0, 0, 0);
        BARRIER();
        cur = nb;
    }

#pragma unroll
    for (int mi = 0; mi < 2; ++mi)
#pragma unroll
        for (int j = 0; j < 4; ++j) {
            float p0 = 0.f, p1 = 0.f;
#pragma unroll
            for (int nj = 0; nj < 4; ++nj) {
                const int col = colbase + nj * 16 + lr;
                const float r = fmaxf(acc[mi][nj][j] + bf[col], 0.f);
                p0 = fmaf(r, Wc[col * 2 + 0], p0);
                p1 = fmaf(r, Wc[col * 2 + 1], p1);
            }
#pragma unroll
            for (int off = 1; off < 16; off <<= 1) {
                p0 += __shfl_xor(p0, off, 64);
                p1 += __shfl_xor(p1, off, 64);
            }
            if (lr == 0) {
                const int row = base + mi * 16 + lk * 4 + j;
                atomicAdd(&out[row * 2 + 0], p0);
                atomicAdd(&out[row * 2 + 1], p1);
            }
        }
}

// ---------------------------------------------------------------------------
extern "C" void kernel_launch(void* const* d_in, const int* in_sizes, int n_in,
                              void* d_out, int out_size, void* d_ws, size_t ws_size,
                              hipStream_t stream)
{
    const float* Xb = (const float*)d_in[0];
    const float* Xc = (const float*)d_in[1];
    // d_in[2] (vec_fcg) intentionally unused: reference source bug reuses cfg.
    const float* Wg = (const float*)d_in[3];
    const float* bg = (const float*)d_in[4];
    const float* W1 = (const float*)d_in[5];
    const float* b1 = (const float*)d_in[6];
    const float* W2 = (const float*)d_in[7];
    const float* b2 = (const float*)d_in[8];
    const float* Wf = (const float*)d_in[9];
    const float* bf = (const float*)d_in[10];
    const float* Wc = (const float*)d_in[11];
    const float* bc = (const float*)d_in[12];
    float* out = (float*)d_out;

    float* ws = (float*)d_ws;
    float* coef_b  = ws;                            // [8][4096]
    float* coef_c  = coef_b + M_EXP * N_TOK;
    float* mask_b  = coef_c + M_EXP * N_TOK;
    float* mask_c  = mask_b + M_EXP * N_TOK;
    float* gpart   = mask_c + M_EXP * N_TOK;        // [2048][8]
    float* cpart   = gpart + 2048 * M_EXP;          // [2048][8]
    float* sum_out = cpart + 2048 * M_EXP;          // [8][256]
    float* out_b   = sum_out + M_EXP * O_DIM;       // [4096][256] f32 (atomic)
    float* out_c   = out_b + (size_t)N_TOK * O_DIM;
    unsigned short* W1T = (unsigned short*)(out_c + (size_t)N_TOK * O_DIM); // [8][256][512]
    unsigned short* W2T = W1T + (size_t)M_EXP * H_DIM * D_IN;               // [8][256][256]
    unsigned short* WfT = W2T + (size_t)M_EXP * O_DIM * H_DIM;              // [512][512]
    unsigned short* Xbf = WfT + (size_t)F_DIM * 512;                        // [2][4096][512]
    unsigned short* Hbuf = Xbf + (size_t)2 * N_TOK * D_IN;                  // [8][4096][256] (reused per mod)

    prep_gate_kernel<<<dim3(4385), 256, 0, stream>>>(
        Xb, Xc, Wg, bg, W1, W2, Wf, bc,
        W1T, W2T, WfT, Xbf,
        coef_b, coef_c, mask_b, mask_c, gpart, cpart,
        out_b /*zero base*/, sum_out, out);

    // modality 0 (binary)
    h_gemm_kernel<<<dim3(512), 256, 0, stream>>>(Xbf, W1T, b1, Hbuf);
    y_gemm_kernel<<<dim3(512), 256, 0, stream>>>(
        Hbuf, W2T, b2, coef_b, mask_b, out_b, sum_out, 1.f);
    // modality 1 (cfg) — Hbuf reused; stream-serialized
    h_gemm_kernel<<<dim3(512), 256, 0, stream>>>(Xbf + (size_t)N_TOK * D_IN, W1T, b1, Hbuf);
    y_gemm_kernel<<<dim3(512), 256, 0, stream>>>(
        Hbuf, W2T, b2, coef_c, mask_c, out_c, sum_out, 2.f);

    fuse_cls_loss_kernel<<<dim3(129, 2), 256, 0, stream>>>(
        out_b, out_c, WfT, bf, Wc, gpart, cpart, sum_out, out);
}

// Round 8
// 92.198 us; speedup vs baseline: 1.7604x; 1.0617x over previous
//
#include <hip/hip_runtime.h>
#include <hip/hip_bf16.h>

// Problem constants: N=4096, D=512, H=256, O=256, M=8, K=2, F=512, C=2
#define N_TOK 4096
#define D_IN  512
#define H_DIM 256
#define O_DIM 256
#define M_EXP 8
#define F_DIM 512

typedef __attribute__((ext_vector_type(8))) short bf16x8;   // 8 bf16 = 4 VGPRs
typedef __attribute__((ext_vector_type(4))) float f32x4;    // MFMA C/D frag

#define VMCNT(n)  asm volatile("s_waitcnt vmcnt(" #n ")" ::: "memory")
#define LGKMCNT0  asm volatile("s_waitcnt lgkmcnt(0)" ::: "memory")
#define BARRIER() __builtin_amdgcn_s_barrier()

// RNE f32 -> bf16 bits
__device__ __forceinline__ unsigned short f2bf(float f) {
    unsigned int u = __float_as_uint(f);
    u = (u + 0x7FFFu + ((u >> 16) & 1u)) >> 16;
    return (unsigned short)u;
}

// async global->LDS, 16B per lane; LDS dest wave-uniform base + lane*16
__device__ __forceinline__ void gload_lds16(const void* g, void* l) {
    __builtin_amdgcn_global_load_lds(
        (const __attribute__((address_space(1))) unsigned int*)g,
        (__attribute__((address_space(3))) unsigned int*)l, 16, 0, 0);
}

// Swizzled LDS byte offset for [R][32 bf16] tiles (64B rows, 4x16B slots).
__device__ __forceinline__ int sw64(int row, int lslot) {
    return row * 64 + ((lslot ^ ((row >> 1) & 3)) << 4);
}
// 1024B rows (64x16B slots): slot ^= row&7.
__device__ __forceinline__ int swAs(int row, int lslot) {
    return row * 1024 + ((lslot ^ (row & 7)) << 4);
}

// ---------------------------------------------------------------------------
// Kernel 1 (merged): weight transposes + WfT fold + out init + zeroing +
// gating (f32-exact, reduction order preserved) + X f32->bf16.
// ---------------------------------------------------------------------------
__global__ __launch_bounds__(256) void prep_gate_kernel(
    const float* __restrict__ Xb, const float* __restrict__ Xc,
    const float* __restrict__ Wg, const float* __restrict__ bg,
    const float* __restrict__ W1, const float* __restrict__ W2,
    const float* __restrict__ Wf, const float* __restrict__ bc,
    unsigned short* __restrict__ W1T, unsigned short* __restrict__ W2T,
    unsigned short* __restrict__ WfT, unsigned short* __restrict__ Xbf,
    float* __restrict__ coef_b, float* __restrict__ coef_c,
    float* __restrict__ mask_b, float* __restrict__ mask_c,
    float* __restrict__ gpart, float* __restrict__ cpart,
    float* __restrict__ zero_base, float* __restrict__ sum_out,
    float* __restrict__ out)
{
    __shared__ float tile[32][33];
    __shared__ float s_g[M_EXP];
    __shared__ float s_c[M_EXP];
    const int bx = blockIdx.x;
    const int tr = threadIdx.x >> 3, q = threadIdx.x & 7;

    if (bx < 1024) {            // W1 [8][512][256] -> W1T [8][256][512]
        const int e = bx >> 7, tidx = bx & 127;
        const int r0 = (tidx >> 3) * 32, c0 = (tidx & 7) * 32;
        const float* s = W1 + (size_t)e * 512 * 256;
        unsigned short* d = W1T + (size_t)e * 512 * 256;
        *(float4*)&tile[tr][q * 4] = *(const float4*)&s[(size_t)(r0 + tr) * 256 + c0 + q * 4];
        __syncthreads();
        ushort4 o;
        o.x = f2bf(tile[q*4+0][tr]); o.y = f2bf(tile[q*4+1][tr]);
        o.z = f2bf(tile[q*4+2][tr]); o.w = f2bf(tile[q*4+3][tr]);
        *(ushort4*)&d[(size_t)(c0 + tr) * 512 + r0 + q * 4] = o;
    } else if (bx < 1536) {     // W2 [8][256][256] -> W2T [8][256][256]
        const int idx = bx - 1024;
        const int e = idx >> 6, tidx = idx & 63;
        const int r0 = (tidx >> 3) * 32, c0 = (tidx & 7) * 32;
        const float* s = W2 + (size_t)e * 256 * 256;
        unsigned short* d = W2T + (size_t)e * 256 * 256;
        *(float4*)&tile[tr][q * 4] = *(const float4*)&s[(size_t)(r0 + tr) * 256 + c0 + q * 4];
        __syncthreads();
        ushort4 o;
        o.x = f2bf(tile[q*4+0][tr]); o.y = f2bf(tile[q*4+1][tr]);
        o.z = f2bf(tile[q*4+2][tr]); o.w = f2bf(tile[q*4+3][tr]);
        *(ushort4*)&d[(size_t)(c0 + tr) * 256 + r0 + q * 4] = o;
    } else if (bx < 1792) {     // WfT_eff[f][j] = Wf[j][f] + (j>=256 ? Wf[j+256][f] : 0)
        const int idx = bx - 1536;
        const int j0 = (idx >> 4) * 32, f0 = (idx & 15) * 32;
        float4 v = *(const float4*)&Wf[(size_t)(j0 + tr) * F_DIM + f0 + q * 4];
        if (j0 >= 256) {
            const float4 v2 = *(const float4*)&Wf[(size_t)(j0 + tr + 256) * F_DIM + f0 + q * 4];
            v.x += v2.x; v.y += v2.y; v.z += v2.z; v.w += v2.w;
        }
        *(float4*)&tile[tr][q * 4] = v;
        __syncthreads();
        ushort4 o;
        o.x = f2bf(tile[q*4+0][tr]); o.y = f2bf(tile[q*4+1][tr]);
        o.z = f2bf(tile[q*4+2][tr]); o.w = f2bf(tile[q*4+3][tr]);
        *(ushort4*)&WfT[(size_t)(f0 + tr) * 512 + j0 + q * 4] = o;
    } else if (bx < 1824) {     // out init
        const int i = (bx - 1792) * 256 + threadIdx.x;
        out[i] = bc[i & 1];
    } else if (bx < 2336) {     // zero out_b/out_c
        float4 z = {0.f, 0.f, 0.f, 0.f};
        float* p = zero_base + (size_t)(bx - 1824) * 4096 + threadIdx.x * 16;
#pragma unroll
        for (int k = 0; k < 4; ++k) *(float4*)(p + k * 4) = z;
    } else if (bx < 2337) {     // zero sum_out
#pragma unroll
        for (int k = 0; k < 8; ++k) sum_out[threadIdx.x * 8 + k] = 0.f;
    } else {                    // ---------------- gating ----------------
        const int idx = bx - 2337;
        const int mod = idx >> 10;
        const int b = idx & 1023;
        const float* X = mod ? Xc : Xb;
        float* coef = mod ? coef_c : coef_b;
        float* mask = mod ? mask_c : mask_b;
        const int wave = threadIdx.x >> 6;
        const int lane = threadIdx.x & 63;
        const int n = b * 4 + wave;

        if (threadIdx.x < M_EXP) { s_g[threadIdx.x] = 0.f; s_c[threadIdx.x] = 0.f; }
        __syncthreads();

        float acc[M_EXP] = {0.f,0.f,0.f,0.f,0.f,0.f,0.f,0.f};
        const float* xrow = X + (size_t)n * D_IN;
        unsigned short* xb = Xbf + (size_t)mod * N_TOK * D_IN + (size_t)n * D_IN;
#pragma unroll
        for (int k = 0; k < 8; ++k) {
            const int d = lane + 64 * k;
            const float xv = xrow[d];
            xb[d] = f2bf(xv);
            const float* wr = Wg + d * M_EXP;
#pragma unroll
            for (int m = 0; m < M_EXP; ++m) acc[m] += xv * wr[m];
        }
#pragma unroll
        for (int off = 1; off < 64; off <<= 1) {
#pragma unroll
            for (int m = 0; m < M_EXP; ++m) acc[m] += __shfl_xor(acc[m], off, 64);
        }
        float g[M_EXP];
        float mx = -1e30f;
#pragma unroll
        for (int m = 0; m < M_EXP; ++m) { g[m] = acc[m] + bg[m]; mx = fmaxf(mx, g[m]); }
        float es = 0.f;
#pragma unroll
        for (int m = 0; m < M_EXP; ++m) { g[m] = expf(g[m] - mx); es += g[m]; }
        const float inv = 1.f / es;
#pragma unroll
        for (int m = 0; m < M_EXP; ++m) g[m] *= inv;

        int i0 = 0; float v0 = g[0];
#pragma unroll
        for (int m = 1; m < M_EXP; ++m) if (g[m] > v0) { v0 = g[m]; i0 = m; }
        int i1 = -1; float v1 = -1e30f;
#pragma unroll
        for (int m = 0; m < M_EXP; ++m) if (m != i0 && g[m] > v1) { v1 = g[m]; i1 = m; }

        if (lane == 0) {
            const float wn = 1.f / (v0 + v1);
#pragma unroll
            for (int m = 0; m < M_EXP; ++m) {   // FULL row write -> no memset
                const float cv = (m == i0) ? v0 * wn : (m == i1) ? v1 * wn : 0.f;
                coef[m * N_TOK + n] = cv;
                mask[m * N_TOK + n] = (m == i0 || m == i1) ? 1.f : 0.f;
            }
#pragma unroll
            for (int m = 0; m < M_EXP; ++m) atomicAdd(&s_g[m], g[m]);
            atomicAdd(&s_c[i0], 1.f);
            atomicAdd(&s_c[i1], 1.f);
        }
        __syncthreads();
        if (threadIdx.x < M_EXP) {
            gpart[idx * M_EXP + threadIdx.x] = s_g[threadIdx.x];
            cpart[idx * M_EXP + threadIdx.x] = s_c[threadIdx.x];
        }
    }
}

// ---------------------------------------------------------------------------
// h-GEMM (both modalities merged): H = relu(X @ W1_all + b1).
// M=8192 (mod-major rows), N=2048, K=512. m97-replica structure: 128x128
// tile, 4 waves (2x2 of 64x64), BK=32, SINGLE-buffered 16KB LDS, plain
// 2-syncthreads loop, global_load_lds w16. Latency hidden by ~4 blocks/CU
// residency (grid 1024). Output Hbuf[2][8][4096][256] bf16 via 32KB LDS
// restage (reuses the A/B space after the loop).
// ---------------------------------------------------------------------------
__global__ __launch_bounds__(256, 4) void h_gemm_kernel(
    const unsigned short* __restrict__ Xbf,    // [8192][512] bf16 (mod-major)
    const unsigned short* __restrict__ W1T,    // flat [2048][512] bf16
    const float* __restrict__ b1,              // flat [2048]
    unsigned short* __restrict__ Hbuf)         // [2][8][4096][256] bf16
{
    __shared__ __align__(16) char lds[32768];  // loop: A @0 (8K), B @8K (8K); epi: C [128][128]bf16

    const int t = threadIdx.x;
    const int w = t >> 6, l = t & 63;
    const int lr = l & 15, lk = l >> 4;
    const int wrow = (w >> 1) * 64, wcol = (w & 1) * 64;

    const int bid = blockIdx.x;                 // 1024 blocks
    const int xcd = bid & 7, j = bid >> 3;      // j 0..127
    const int rt = xcd * 8 + (j & 7);           // 0..63  (1MB A rows per XCD)
    const int ct = j >> 3;                      // 0..15  (full W1T per XCD, 2MB)
    const int r0 = rt * 128, c0 = ct * 128;

    float bv[4];
#pragma unroll
    for (int nj = 0; nj < 4; ++nj) bv[nj] = b1[c0 + wcol + nj * 16 + lr];

    const int srow = l >> 2;                    // 0..15
    const int sslot = l & 3;

    f32x4 acc[4][4];
#pragma unroll
    for (int mi = 0; mi < 4; ++mi)
#pragma unroll
        for (int nj = 0; nj < 4; ++nj) { f32x4 z = {0.f,0.f,0.f,0.f}; acc[mi][nj] = z; }

    for (int kc = 0; kc < 16; ++kc) {
        // stage A and B chunks [128][32] each (4 gloads/wave)
#pragma unroll
        for (int s = 0; s < 2; ++s) {
            const int row = w * 32 + s * 16 + srow;
            const int lsA = sslot ^ ((row >> 1) & 3);
            gload_lds16(Xbf + (size_t)(r0 + row) * 512 + kc * 32 + lsA * 8,
                        lds + w * 2048 + s * 1024);
            gload_lds16(W1T + (size_t)(c0 + row) * 512 + kc * 32 + lsA * 8,
                        lds + 8192 + w * 2048 + s * 1024);
        }
        __syncthreads();
        bf16x8 a[4], b[4];
#pragma unroll
        for (int mi = 0; mi < 4; ++mi)
            a[mi] = *(const bf16x8*)(lds + sw64(wrow + mi * 16 + lr, lk));
#pragma unroll
        for (int nj = 0; nj < 4; ++nj)
            b[nj] = *(const bf16x8*)(lds + 8192 + sw64(wcol + nj * 16 + lr, lk));
#pragma unroll
        for (int mi = 0; mi < 4; ++mi)
#pragma unroll
            for (int nj = 0; nj < 4; ++nj)
                acc[mi][nj] = __builtin_amdgcn_mfma_f32_16x16x32_bf16(a[mi], b[nj], acc[mi][nj], 0, 0, 0);
        __syncthreads();
    }

    // epilogue: relu(acc+b1) -> bf16 -> LDS C [128][128] -> vectorized store
#pragma unroll
    for (int mi = 0; mi < 4; ++mi)
#pragma unroll
        for (int nj = 0; nj < 4; ++nj) {
            const int col = wcol + nj * 16 + lr;
#pragma unroll
            for (int j2 = 0; j2 < 4; ++j2) {
                const int row = wrow + mi * 16 + lk * 4 + j2;
                *(unsigned short*)(lds + row * 256 + col * 2) =
                    f2bf(fmaxf(acc[mi][nj][j2] + bv[nj], 0.f));
            }
        }
    __syncthreads();
    {
        const int e = ct >> 1, hc0 = (ct & 1) * 128;
#pragma unroll
        for (int q2 = 0; q2 < 8; ++q2) {
            const int u = q2 * 256 + t;         // 2048 16B units
            const int row = u >> 4, cs = u & 15;
            const int gr = r0 + row;            // global row in 8192
            const int mod = gr >> 12, n = gr & 4095;
            *(bf16x8*)(Hbuf + (((size_t)(mod * 8 + e) * 4096 + n) * 256 + hc0 + cs * 8)) =
                *(const bf16x8*)(lds + u * 16);
        }
    }
}

// ---------------------------------------------------------------------------
// y-GEMM (both modalities, grouped per expert): Y = Hbuf[mod][e] @ W2[e] + b2.
// 128x128 tile, K=256 -> 8 chunks, same m97 single-buffer structure.
// Epilogue: top-k combine (predicated atomics) + masked col sums.
// ---------------------------------------------------------------------------
__global__ __launch_bounds__(256, 4) void y_gemm_kernel(
    const unsigned short* __restrict__ Hbuf,   // [2][8][4096][256] bf16
    const unsigned short* __restrict__ W2T,    // [8][256][256] bf16
    const float* __restrict__ b2,              // [8][256]
    const float* __restrict__ coef_b, const float* __restrict__ coef_c,
    const float* __restrict__ mask_b, const float* __restrict__ mask_c,
    float* __restrict__ out_b, float* __restrict__ out_c,
    float* __restrict__ sum_out)
{
    __shared__ __align__(16) char lds[16384];  // A @0 (8K), B @8K (8K)

    const int t = threadIdx.x;
    const int w = t >> 6, l = t & 63;
    const int lr = l & 15, lk = l >> 4;
    const int wrow = (w >> 1) * 64, wcol = (w & 1) * 64;

    const int bid = blockIdx.x;                 // 1024 blocks
    const int xcd = bid & 7, j = bid >> 3;      // j 0..127
    const int mt = xcd * 4 + (j & 3);           // 0..31
    const int rest = j >> 2;                    // 0..31
    const int nt = rest & 1;
    const int me = rest >> 1;                   // 0..15
    const int e = me & 7, mod = me >> 3;
    const int r0 = mt * 128, oc0 = nt * 128;

    const unsigned short* Amod = Hbuf + (size_t)(mod * 8 + e) * 4096 * 256;
    const unsigned short* Bmod = W2T + (size_t)e * 256 * 256;
    const float* coef = mod ? coef_c : coef_b;
    const float* mask = mod ? mask_c : mask_b;
    float* outp = mod ? out_c : out_b;
    const float modw = mod ? 2.f : 1.f;

    float bv[4];
#pragma unroll
    for (int nj = 0; nj < 4; ++nj) bv[nj] = b2[e * 256 + oc0 + wcol + nj * 16 + lr];

    const int srow = l >> 2;
    const int sslot = l & 3;

    f32x4 acc[4][4];
#pragma unroll
    for (int mi = 0; mi < 4; ++mi)
#pragma unroll
        for (int nj = 0; nj < 4; ++nj) { f32x4 z = {0.f,0.f,0.f,0.f}; acc[mi][nj] = z; }

    for (int kc = 0; kc < 8; ++kc) {
#pragma unroll
        for (int s = 0; s < 2; ++s) {
            const int row = w * 32 + s * 16 + srow;
            const int lsA = sslot ^ ((row >> 1) & 3);
            gload_lds16(Amod + (size_t)(r0 + row) * 256 + kc * 32 + lsA * 8,
                        lds + w * 2048 + s * 1024);
            gload_lds16(Bmod + (size_t)(oc0 + row) * 256 + kc * 32 + lsA * 8,
                        lds + 8192 + w * 2048 + s * 1024);
        }
        __syncthreads();
        bf16x8 a[4], b[4];
#pragma unroll
        for (int mi = 0; mi < 4; ++mi)
            a[mi] = *(const bf16x8*)(lds + sw64(wrow + mi * 16 + lr, lk));
#pragma unroll
        for (int nj = 0; nj < 4; ++nj)
            b[nj] = *(const bf16x8*)(lds + 8192 + sw64(wcol + nj * 16 + lr, lk));
#pragma unroll
        for (int mi = 0; mi < 4; ++mi)
#pragma unroll
            for (int nj = 0; nj < 4; ++nj)
                acc[mi][nj] = __builtin_amdgcn_mfma_f32_16x16x32_bf16(a[mi], b[nj], acc[mi][nj], 0, 0, 0);
        __syncthreads();
    }

    // epilogue: top-k combine + masked column sums
    float sacc[4] = {0.f, 0.f, 0.f, 0.f};
#pragma unroll
    for (int mi = 0; mi < 4; ++mi)
#pragma unroll
        for (int j2 = 0; j2 < 4; ++j2) {
            const int n = r0 + wrow + mi * 16 + lk * 4 + j2;
            const float cf = coef[(size_t)e * N_TOK + n];
            const float mk = mask[(size_t)e * N_TOK + n];
            const size_t grow = (size_t)n * O_DIM;
#pragma unroll
            for (int nj = 0; nj < 4; ++nj) {
                const float v = acc[mi][nj][j2] + bv[nj];
                const int col = oc0 + wcol + nj * 16 + lr;
                if (cf != 0.f) atomicAdd(&outp[grow + col], cf * v);
                sacc[nj] = fmaf(mk, v, sacc[nj]);
            }
        }
#pragma unroll
    for (int nj = 0; nj < 4; ++nj) {
        sacc[nj] += __shfl_xor(sacc[nj], 16, 64);
        sacc[nj] += __shfl_xor(sacc[nj], 32, 64);
    }
    if (lk == 0) {
#pragma unroll
        for (int nj = 0; nj < 4; ++nj)
            atomicAdd(&sum_out[e * O_DIM + oc0 + wcol + nj * 16 + lr], sacc[nj] * modw);
    }
}

// ---------------------------------------------------------------------------
// Fusion + classifier (x<128) + losses (block x==128,y==0). Unchanged.
// ---------------------------------------------------------------------------
__global__ __launch_bounds__(256, 2) void fuse_cls_loss_kernel(
    const float* __restrict__ out_b, const float* __restrict__ out_c,
    const unsigned short* __restrict__ WfT, const float* __restrict__ bf,
    const float* __restrict__ Wc,
    const float* __restrict__ gpart, const float* __restrict__ cpart,
    const float* __restrict__ sum_out, float* __restrict__ out)
{
    __shared__ __align__(16) char As[32 * 1024];
    __shared__ __align__(16) char Ws[2][16384];
    __shared__ float avg[M_EXP][O_DIM];
    __shared__ float partl[256];
    __shared__ float rho_s[M_EXP], rhohat_s[M_EXP];
    __shared__ float simv[28], prs[28];

    const int t = threadIdx.x;

    if (blockIdx.x == 128) {                       // ---------- loss ----------
        if (blockIdx.y != 0) return;
        const int e = t & 7, grp = t >> 3;
        float sg = 0.f, sc = 0.f;
        for (int b2 = grp * 64; b2 < grp * 64 + 64; ++b2) {
            const float wgt = (b2 < 1024) ? 1.f : 2.f;
            sg += wgt * gpart[b2 * 8 + e];
            sc += wgt * cpart[b2 * 8 + e];
        }
        partl[t] = sg; __syncthreads();
        if (t < 8) { float s = 0.f; for (int g2 = 0; g2 < 32; ++g2) s += partl[t + 8 * g2]; rhohat_s[t] = s; }
        __syncthreads();
        partl[t] = sc; __syncthreads();
        if (t < 8) { float s = 0.f; for (int g2 = 0; g2 < 32; ++g2) s += partl[t + 8 * g2]; rho_s[t] = s; }
        __syncthreads();
        for (int idx = t; idx < M_EXP * O_DIM; idx += 256)
            avg[idx >> 8][idx & 255] = sum_out[idx] / fmaxf(rho_s[idx >> 8], 1.f);
        __syncthreads();
        if (t < 28) {
            int a = 0, p = t;
            while (p >= 7 - a) { p -= 7 - a; ++a; }
            const int b = a + 1 + p;
            float d2 = 0.f;
            for (int o = 0; o < O_DIM; ++o) {
                const float df = avg[a][o] - avg[b][o];
                d2 = fmaf(df, df, d2);
            }
            const bool pr = (rho_s[a] > 0.f) && (rho_s[b] > 0.f);
            simv[t] = pr ? expf(-0.5f * d2) : 0.f;
            prs[t]  = pr ? 1.f : 0.f;
        }
        __syncthreads();
        if (t == 0) {
            float s = 0.f, np = 0.f;
            for (int p = 0; p < 28; ++p) { s += simv[p]; np += prs[p]; }
            out[N_TOK * 2 + 0] = -s / fmaxf(np, 1.f);
            float eq = 0.f;
            for (int m = 0; m < M_EXP; ++m) eq = fmaf(rho_s[m], rhohat_s[m], eq);
            out[N_TOK * 2 + 1] = eq / (float)M_EXP;
        }
        return;
    }

    // ---------- fusion + classifier ----------
    const int w = t >> 6, l = t & 63;
    const int lr = l & 15, lk = l >> 4;
    const int base = blockIdx.x * 32;
    const int half = blockIdx.y;
    const int colbase = half * 256 + w * 64;
    const unsigned short* wfp = WfT + (size_t)half * 256 * 512;

    const int wrl = l >> 2;
    const int wp = l & 3;
    auto stage_w = [&](int kc, int buf) {
#pragma unroll
        for (int s2 = 0; s2 < 4; ++s2) {
            const int row = w * 64 + s2 * 16 + wrl;
            const int lslot = wp ^ ((row >> 1) & 3);
            gload_lds16(wfp + (size_t)row * 512 + kc * 32 + lslot * 8,
                        &Ws[buf][w * 4096 + s2 * 1024]);
        }
    };

    stage_w(0, 0);

    {   // A stage: 32x512 f32 -> bf16 LDS (once)
        const int r = t >> 3;
        const int c0 = (t & 7) * 64;
        const float* srcb = (c0 < 256) ? (out_b + (size_t)(base + r) * 256 + c0)
                                       : (out_c + (size_t)(base + r) * 256 + (c0 - 256));
#pragma unroll
        for (int q = 0; q < 8; ++q) {
            const float4 f0 = *(const float4*)(srcb + q * 8);
            const float4 f1 = *(const float4*)(srcb + q * 8 + 4);
            bf16x8 p;
            p[0] = (short)f2bf(f0.x); p[1] = (short)f2bf(f0.y);
            p[2] = (short)f2bf(f0.z); p[3] = (short)f2bf(f0.w);
            p[4] = (short)f2bf(f1.x); p[5] = (short)f2bf(f1.y);
            p[6] = (short)f2bf(f1.z); p[7] = (short)f2bf(f1.w);
            const int s = (t & 7) * 8 + q;
            *(bf16x8*)&As[swAs(r, s)] = p;
        }
    }
    LGKMCNT0;

    f32x4 acc[2][4];
#pragma unroll
    for (int mi = 0; mi < 2; ++mi)
#pragma unroll
        for (int nj = 0; nj < 4; ++nj) { f32x4 z = {0.f,0.f,0.f,0.f}; acc[mi][nj] = z; }

    int cur = 0;
#pragma unroll
    for (int kc = 0; kc < 16; ++kc) {
        const int nb = cur ^ 1;
        if (kc < 15) { stage_w(kc + 1, nb); VMCNT(4); }
        else         { VMCNT(0); }
        BARRIER();
        bf16x8 a[2], b[4];
#pragma unroll
        for (int mi = 0; mi < 2; ++mi)
            a[mi] = *(const bf16x8*)&As[swAs(mi * 16 + lr, kc * 4 + lk)];
#pragma unroll
        for (int nj = 0; nj < 4; ++nj)
            b[nj] = *(const bf16x8*)&Ws[cur][sw64(w * 64 + nj * 16 + lr, lk)];
#pragma unroll
        for (int mi = 0; mi < 2; ++mi)
#pragma unroll
            for (int nj = 0; nj < 4; ++nj)
                acc[mi][nj] = __builtin_amdgcn_mfma_f32_16x16x32_bf16(a[mi], b[nj], acc[mi][nj], 0, 0, 0);
        BARRIER();
        cur = nb;
    }

#pragma unroll
    for (int mi = 0; mi < 2; ++mi)
#pragma unroll
        for (int j = 0; j < 4; ++j) {
            float p0 = 0.f, p1 = 0.f;
#pragma unroll
            for (int nj = 0; nj < 4; ++nj) {
                const int col = colbase + nj * 16 + lr;
                const float r = fmaxf(acc[mi][nj][j] + bf[col], 0.f);
                p0 = fmaf(r, Wc[col * 2 + 0], p0);
                p1 = fmaf(r, Wc[col * 2 + 1], p1);
            }
#pragma unroll
            for (int off = 1; off < 16; off <<= 1) {
                p0 += __shfl_xor(p0, off, 64);
                p1 += __shfl_xor(p1, off, 64);
            }
            if (lr == 0) {
                const int row = base + mi * 16 + lk * 4 + j;
                atomicAdd(&out[row * 2 + 0], p0);
                atomicAdd(&out[row * 2 + 1], p1);
            }
        }
}

// ---------------------------------------------------------------------------
extern "C" void kernel_launch(void* const* d_in, const int* in_sizes, int n_in,
                              void* d_out, int out_size, void* d_ws, size_t ws_size,
                              hipStream_t stream)
{
    const float* Xb = (const float*)d_in[0];
    const float* Xc = (const float*)d_in[1];
    // d_in[2] (vec_fcg) intentionally unused: reference source bug reuses cfg.
    const float* Wg = (const float*)d_in[3];
    const float* bg = (const float*)d_in[4];
    const float* W1 = (const float*)d_in[5];
    const float* b1 = (const float*)d_in[6];
    const float* W2 = (const float*)d_in[7];
    const float* b2 = (const float*)d_in[8];
    const float* Wf = (const float*)d_in[9];
    const float* bf = (const float*)d_in[10];
    const float* Wc = (const float*)d_in[11];
    const float* bc = (const float*)d_in[12];
    float* out = (float*)d_out;

    float* ws = (float*)d_ws;
    float* coef_b  = ws;                            // [8][4096]
    float* coef_c  = coef_b + M_EXP * N_TOK;
    float* mask_b  = coef_c + M_EXP * N_TOK;
    float* mask_c  = mask_b + M_EXP * N_TOK;
    float* gpart   = mask_c + M_EXP * N_TOK;        // [2048][8]
    float* cpart   = gpart + 2048 * M_EXP;          // [2048][8]
    float* sum_out = cpart + 2048 * M_EXP;          // [8][256]
    float* out_b   = sum_out + M_EXP * O_DIM;       // [4096][256] f32 (atomic)
    float* out_c   = out_b + (size_t)N_TOK * O_DIM;
    unsigned short* W1T = (unsigned short*)(out_c + (size_t)N_TOK * O_DIM); // [8][256][512]
    unsigned short* W2T = W1T + (size_t)M_EXP * H_DIM * D_IN;               // [8][256][256]
    unsigned short* WfT = W2T + (size_t)M_EXP * O_DIM * H_DIM;              // [512][512]
    unsigned short* Xbf = WfT + (size_t)F_DIM * 512;                        // [2][4096][512]
    unsigned short* Hbuf = Xbf + (size_t)2 * N_TOK * D_IN;                  // [2][8][4096][256]

    prep_gate_kernel<<<dim3(4385), 256, 0, stream>>>(
        Xb, Xc, Wg, bg, W1, W2, Wf, bc,
        W1T, W2T, WfT, Xbf,
        coef_b, coef_c, mask_b, mask_c, gpart, cpart,
        out_b /*zero base*/, sum_out, out);

    h_gemm_kernel<<<dim3(1024), 256, 0, stream>>>(Xbf, W1T, b1, Hbuf);
    y_gemm_kernel<<<dim3(1024), 256, 0, stream>>>(
        Hbuf, W2T, b2, coef_b, coef_c, mask_b, mask_c, out_b, out_c, sum_out);

    fuse_cls_loss_kernel<<<dim3(129, 2), 256, 0, stream>>>(
        out_b, out_c, WfT, bf, Wc, gpart, cpart, sum_out, out);
}